// Round 1
// baseline (2740.975 us; speedup 1.0000x reference)
//
#include <hip/hip_runtime.h>

// AttentionBlock: x(4,256,64,64) fp32
//   qkv = w_qkv(768,256) @ x   -> q,k,v  (heads=4, d=64, hw=4096)
//   attn = softmax(q k^T / 8) v   (per b,head; N=4096, d=64)
//   out  = x + w_out @ attn_out + b_out
//
// ws layout (fp32): q[16][64][4096] | k[...] | v[...] | att[...]  = 64 MB
// All ws tensors indexed [bh][dd][p] where bh = b*4+head, p = h*64+w.

#define HW 4096
#define CIN 256
#define NSEQ 4096
#define HEADSZ (64 * HW)   // floats per (b,head) plane

// ---------------------------------------------------------------------------
// Kernel 1: qkv projection. O[o,p] = sum_c W[o,c] * X[b,c,p], o in [0,768)
// 64x64 output tile per block, 4x4 per thread, K staged in chunks of 64.
// Scatter epilogue into q/k/v ws planes.
// ---------------------------------------------------------------------------
__global__ __launch_bounds__(256) void qkv_gemm_k(
    const float* __restrict__ x, const float* __restrict__ w,
    float* __restrict__ qws, float* __restrict__ kws, float* __restrict__ vws)
{
    const int o0 = blockIdx.x * 64;
    const int p0 = blockIdx.y * 64;
    const int b  = blockIdx.z;
    const int t  = threadIdx.x;
    const int tx = t & 15, ty = t >> 4;

    __shared__ float wt[64 * 65];  // [cc][oo], pad 65 -> conflict-free transpose
    __shared__ float xs[64 * 64];  // [cc][pp]

    float acc[4][4] = {};
    const float* xb = x + (size_t)b * CIN * HW;

    for (int kc = 0; kc < 4; ++kc) {
        __syncthreads();
        // stage W chunk transposed: wt[cc][oo] = w[o0+oo][kc*64+cc]
        for (int iter = 0; iter < 4; ++iter) {
            int idx = iter * 1024 + t * 4;
            int oo = idx >> 6, cc = idx & 63;
            const float4 wv = *(const float4*)&w[(o0 + oo) * CIN + kc * 64 + cc];
            wt[(cc + 0) * 65 + oo] = wv.x;
            wt[(cc + 1) * 65 + oo] = wv.y;
            wt[(cc + 2) * 65 + oo] = wv.z;
            wt[(cc + 3) * 65 + oo] = wv.w;
        }
        // stage X chunk: xs[cc][pp] = x[b][kc*64+cc][p0+pp]
        for (int iter = 0; iter < 4; ++iter) {
            int idx = iter * 1024 + t * 4;
            int cc = idx >> 6, pp = idx & 63;
            *(float4*)&xs[idx] = *(const float4*)&xb[(size_t)(kc * 64 + cc) * HW + p0 + pp];
        }
        __syncthreads();

        #pragma unroll 8
        for (int cc = 0; cc < 64; ++cc) {
            const float w0 = wt[cc * 65 + ty * 4 + 0];
            const float w1 = wt[cc * 65 + ty * 4 + 1];
            const float w2 = wt[cc * 65 + ty * 4 + 2];
            const float w3 = wt[cc * 65 + ty * 4 + 3];
            const float4 xv = *(const float4*)&xs[cc * 64 + tx * 4];
            acc[0][0] += w0 * xv.x; acc[0][1] += w0 * xv.y; acc[0][2] += w0 * xv.z; acc[0][3] += w0 * xv.w;
            acc[1][0] += w1 * xv.x; acc[1][1] += w1 * xv.y; acc[1][2] += w1 * xv.z; acc[1][3] += w1 * xv.w;
            acc[2][0] += w2 * xv.x; acc[2][1] += w2 * xv.y; acc[2][2] += w2 * xv.z; acc[2][3] += w2 * xv.w;
            acc[3][0] += w3 * xv.x; acc[3][1] += w3 * xv.y; acc[3][2] += w3 * xv.z; acc[3][3] += w3 * xv.w;
        }
    }

    // scatter: o -> (which, head, dd); write [bh][dd][p] contiguous in p
    #pragma unroll
    for (int i = 0; i < 4; ++i) {
        const int o = o0 + ty * 4 + i;
        const int which = o >> 8;
        const int ch = o & 255;
        float* dst = (which == 0) ? qws : (which == 1) ? kws : vws;
        float4 val;
        val.x = acc[i][0]; val.y = acc[i][1]; val.z = acc[i][2]; val.w = acc[i][3];
        *(float4*)&dst[(size_t)((b * 4 + (ch >> 6)) * 64 + (ch & 63)) * HW + p0 + tx * 4] = val;
    }
}

// ---------------------------------------------------------------------------
// Kernel 2: flash attention per (bh, i-tile of 128 rows).
// 256 threads: 2 threads per Q-row, each owns 32 of d. Online softmax.
// K/V tiles (64 j) staged in LDS as [dd][jj]; all compute reads are
// wave-uniform broadcasts (or 2-way: free).
// ---------------------------------------------------------------------------
__global__ __launch_bounds__(256) void flash_k(
    const float* __restrict__ q, const float* __restrict__ k,
    const float* __restrict__ v, float* __restrict__ o)
{
    const int i0 = blockIdx.x * 128;  // 32 tiles
    const int bh = blockIdx.y;        // 16
    const int t  = threadIdx.x;
    const int rl = t >> 1;            // local row 0..127
    const int db = (t & 1) * 32;      // d-half base

    const float* qg = q + (size_t)bh * HEADSZ;
    const float* kg = k + (size_t)bh * HEADSZ;
    const float* vg = v + (size_t)bh * HEADSZ;
    float*       og = o + (size_t)bh * HEADSZ;

    __shared__ float lds[8192];       // Q staging [64][128], then K[0:4096]|V[4096:8192]

    // stage Q tile [dd][ii] and pull own row (scaled) into registers
    for (int iter = 0; iter < 8; ++iter) {
        int idx = iter * 1024 + t * 4;
        int dd = idx >> 7, ii = idx & 127;
        *(float4*)&lds[idx] = *(const float4*)&qg[(size_t)dd * HW + i0 + ii];
    }
    __syncthreads();
    float qreg[32];
    #pragma unroll
    for (int d2 = 0; d2 < 32; ++d2) qreg[d2] = lds[(db + d2) * 128 + rl] * 0.125f;

    float m = -1e30f, l = 0.0f;
    float acc[32] = {};

    float* klds = lds;
    float* vlds = lds + 4096;

    for (int jt = 0; jt < 64; ++jt) {
        __syncthreads();   // previous tile fully consumed
        for (int iter = 0; iter < 4; ++iter) {
            int idx = iter * 1024 + t * 4;
            int dd = idx >> 6, jj = idx & 63;
            *(float4*)&klds[idx] = *(const float4*)&kg[(size_t)dd * HW + jt * 64 + jj];
            *(float4*)&vlds[idx] = *(const float4*)&vg[(size_t)dd * HW + jt * 64 + jj];
        }
        __syncthreads();

        for (int jg = 0; jg < 4; ++jg) {
            // --- QK^T: 16 scores (partial over own 32 dims) ---
            float s[16];
            #pragma unroll
            for (int j4 = 0; j4 < 16; j4 += 4) {
                float4 a4 = {0.f, 0.f, 0.f, 0.f};
                #pragma unroll
                for (int d2 = 0; d2 < 32; ++d2) {
                    const float4 kv = *(const float4*)&klds[(db + d2) * 64 + jg * 16 + j4];
                    const float qd = qreg[d2];
                    a4.x += qd * kv.x; a4.y += qd * kv.y; a4.z += qd * kv.z; a4.w += qd * kv.w;
                }
                s[j4 + 0] = a4.x; s[j4 + 1] = a4.y; s[j4 + 2] = a4.z; s[j4 + 3] = a4.w;
            }
            // combine d-halves (lane pairs)
            #pragma unroll
            for (int idx = 0; idx < 16; ++idx) s[idx] += __shfl_xor(s[idx], 1, 64);

            // --- online softmax update ---
            float tmax = s[0];
            #pragma unroll
            for (int idx = 1; idx < 16; ++idx) tmax = fmaxf(tmax, s[idx]);
            const float mnew = fmaxf(m, tmax);
            const float f = __expf(m - mnew);
            m = mnew;
            l *= f;
            #pragma unroll
            for (int idx = 0; idx < 16; ++idx) {
                const float p = __expf(s[idx] - mnew);
                s[idx] = p;
                l += p;
            }
            // --- PV (rescale folded in) ---
            #pragma unroll
            for (int d2 = 0; d2 < 32; ++d2) {
                float a = acc[d2] * f;
                #pragma unroll
                for (int j4 = 0; j4 < 16; j4 += 4) {
                    const float4 vv = *(const float4*)&vlds[(db + d2) * 64 + jg * 16 + j4];
                    a += s[j4 + 0] * vv.x + s[j4 + 1] * vv.y + s[j4 + 2] * vv.z + s[j4 + 3] * vv.w;
                }
                acc[d2] = a;
            }
        }
    }

    const float inv = 1.0f / l;
    #pragma unroll
    for (int d2 = 0; d2 < 32; ++d2)
        og[(size_t)(db + d2) * HW + i0 + rl] = acc[d2] * inv;
}

// ---------------------------------------------------------------------------
// Kernel 3: out = x + w_out @ att + b_out. Same GEMM structure, O=256.
// ---------------------------------------------------------------------------
__global__ __launch_bounds__(256) void proj_gemm_k(
    const float* __restrict__ att, const float* __restrict__ w,
    const float* __restrict__ bias, const float* __restrict__ x,
    float* __restrict__ out)
{
    const int o0 = blockIdx.x * 64;
    const int p0 = blockIdx.y * 64;
    const int b  = blockIdx.z;
    const int t  = threadIdx.x;
    const int tx = t & 15, ty = t >> 4;

    __shared__ float wt[64 * 65];
    __shared__ float xs[64 * 64];

    float acc[4][4] = {};
    const float* ab = att + (size_t)b * CIN * HW;

    for (int kc = 0; kc < 4; ++kc) {
        __syncthreads();
        for (int iter = 0; iter < 4; ++iter) {
            int idx = iter * 1024 + t * 4;
            int oo = idx >> 6, cc = idx & 63;
            const float4 wv = *(const float4*)&w[(o0 + oo) * CIN + kc * 64 + cc];
            wt[(cc + 0) * 65 + oo] = wv.x;
            wt[(cc + 1) * 65 + oo] = wv.y;
            wt[(cc + 2) * 65 + oo] = wv.z;
            wt[(cc + 3) * 65 + oo] = wv.w;
        }
        for (int iter = 0; iter < 4; ++iter) {
            int idx = iter * 1024 + t * 4;
            int cc = idx >> 6, pp = idx & 63;
            *(float4*)&xs[idx] = *(const float4*)&ab[(size_t)(kc * 64 + cc) * HW + p0 + pp];
        }
        __syncthreads();

        #pragma unroll 8
        for (int cc = 0; cc < 64; ++cc) {
            const float w0 = wt[cc * 65 + ty * 4 + 0];
            const float w1 = wt[cc * 65 + ty * 4 + 1];
            const float w2 = wt[cc * 65 + ty * 4 + 2];
            const float w3 = wt[cc * 65 + ty * 4 + 3];
            const float4 xv = *(const float4*)&xs[cc * 64 + tx * 4];
            acc[0][0] += w0 * xv.x; acc[0][1] += w0 * xv.y; acc[0][2] += w0 * xv.z; acc[0][3] += w0 * xv.w;
            acc[1][0] += w1 * xv.x; acc[1][1] += w1 * xv.y; acc[1][2] += w1 * xv.z; acc[1][3] += w1 * xv.w;
            acc[2][0] += w2 * xv.x; acc[2][1] += w2 * xv.y; acc[2][2] += w2 * xv.z; acc[2][3] += w2 * xv.w;
            acc[3][0] += w3 * xv.x; acc[3][1] += w3 * xv.y; acc[3][2] += w3 * xv.z; acc[3][3] += w3 * xv.w;
        }
    }

    #pragma unroll
    for (int i = 0; i < 4; ++i) {
        const int o = o0 + ty * 4 + i;
        const float bo = bias[o];
        const size_t base = (size_t)(b * CIN + o) * HW + p0 + tx * 4;
        const float4 xv = *(const float4*)&x[base];
        float4 val;
        val.x = acc[i][0] + bo + xv.x;
        val.y = acc[i][1] + bo + xv.y;
        val.z = acc[i][2] + bo + xv.z;
        val.w = acc[i][3] + bo + xv.w;
        *(float4*)&out[base] = val;
    }
}

extern "C" void kernel_launch(void* const* d_in, const int* in_sizes, int n_in,
                              void* d_out, int out_size, void* d_ws, size_t ws_size,
                              hipStream_t stream)
{
    const float* x     = (const float*)d_in[0];
    const float* w_qkv = (const float*)d_in[1];
    const float* w_out = (const float*)d_in[2];
    const float* b_out = (const float*)d_in[3];
    float* out = (float*)d_out;

    float* ws  = (float*)d_ws;
    const size_t PLANE = (size_t)16 * 64 * HW;  // 4,194,304 floats
    float* qws = ws;
    float* kws = ws + PLANE;
    float* vws = ws + 2 * PLANE;
    float* att = ws + 3 * PLANE;

    // K1: qkv projection  (768/64=12 o-tiles, 4096/64=64 p-tiles, 4 batches)
    qkv_gemm_k<<<dim3(12, 64, 4), 256, 0, stream>>>(x, w_qkv, qws, kws, vws);

    // K2: flash attention (32 i-tiles x 16 bh)
    flash_k<<<dim3(32, 16), 256, 0, stream>>>(qws, kws, vws, att);

    // K3: output projection + bias + residual
    proj_gemm_k<<<dim3(4, 64, 4), 256, 0, stream>>>(att, w_out, b_out, x, out);
}

// Round 2
// 268.401 us; speedup vs baseline: 10.2122x; 10.2122x over previous
//
#include <hip/hip_runtime.h>

// AttentionBlock: x(4,256,64,64) fp32
//   qkv = w_qkv(768,256) @ x ; per-head flash attention (N=4096, d=64, 16 bh);
//   out = x + w_out @ att + b_out
//
// ws: Qb bf16 [bh][p][64] (pre-scaled 1/8) | Kb bf16 [bh][p][64] |
//     Vb bf16 [bh][64][p] | att f32 [bh][64][p]

#define HW 4096
#define CIN 256

typedef __attribute__((ext_vector_type(8))) short short8v;
typedef __attribute__((ext_vector_type(4))) short short4v;
typedef __attribute__((ext_vector_type(4))) float float4v;

static __device__ __forceinline__ unsigned short f2bf(float f) {
    unsigned int u = __float_as_uint(f);
    u += 0x7fff + ((u >> 16) & 1);   // round-to-nearest-even
    return (unsigned short)(u >> 16);
}

// ---------------------------------------------------------------------------
// Kernel 1: qkv projection (fp32 VALU GEMM), epilogue packs bf16.
// Each block covers one 64-wide o-range -> exactly one tensor+head.
// ---------------------------------------------------------------------------
__global__ __launch_bounds__(256) void qkv_gemm_k(
    const float* __restrict__ x, const float* __restrict__ w,
    unsigned short* __restrict__ qb, unsigned short* __restrict__ kb,
    unsigned short* __restrict__ vb)
{
    const int o0 = blockIdx.x * 64;
    const int p0 = blockIdx.y * 64;
    const int b  = blockIdx.z;
    const int t  = threadIdx.x;
    const int tx = t & 15, ty = t >> 4;

    __shared__ float wt[64 * 65];
    __shared__ float xs[64 * 64];

    float acc[4][4] = {};
    const float* xb = x + (size_t)b * CIN * HW;

    for (int kc = 0; kc < 4; ++kc) {
        __syncthreads();
        for (int iter = 0; iter < 4; ++iter) {
            int idx = iter * 1024 + t * 4;
            int oo = idx >> 6, cc = idx & 63;
            const float4 wv = *(const float4*)&w[(o0 + oo) * CIN + kc * 64 + cc];
            wt[(cc + 0) * 65 + oo] = wv.x;
            wt[(cc + 1) * 65 + oo] = wv.y;
            wt[(cc + 2) * 65 + oo] = wv.z;
            wt[(cc + 3) * 65 + oo] = wv.w;
        }
        for (int iter = 0; iter < 4; ++iter) {
            int idx = iter * 1024 + t * 4;
            int cc = idx >> 6, pp = idx & 63;
            *(float4*)&xs[idx] = *(const float4*)&xb[(size_t)(kc * 64 + cc) * HW + p0 + pp];
        }
        __syncthreads();

        #pragma unroll 8
        for (int cc = 0; cc < 64; ++cc) {
            const float w0 = wt[cc * 65 + ty * 4 + 0];
            const float w1 = wt[cc * 65 + ty * 4 + 1];
            const float w2 = wt[cc * 65 + ty * 4 + 2];
            const float w3 = wt[cc * 65 + ty * 4 + 3];
            const float4 xv = *(const float4*)&xs[cc * 64 + tx * 4];
            acc[0][0] += w0 * xv.x; acc[0][1] += w0 * xv.y; acc[0][2] += w0 * xv.z; acc[0][3] += w0 * xv.w;
            acc[1][0] += w1 * xv.x; acc[1][1] += w1 * xv.y; acc[1][2] += w1 * xv.z; acc[1][3] += w1 * xv.w;
            acc[2][0] += w2 * xv.x; acc[2][1] += w2 * xv.y; acc[2][2] += w2 * xv.z; acc[2][3] += w2 * xv.w;
            acc[3][0] += w3 * xv.x; acc[3][1] += w3 * xv.y; acc[3][2] += w3 * xv.z; acc[3][3] += w3 * xv.w;
        }
    }

    const int which = o0 >> 8;            // 0=q 1=k 2=v
    const int head  = (o0 >> 6) & 3;
    const int bh    = b * 4 + head;
    if (which == 2) {
        // V: d-major [bh][dd][p]
        #pragma unroll
        for (int i = 0; i < 4; ++i) {
            short4v pk;
            pk[0] = (short)f2bf(acc[i][0]); pk[1] = (short)f2bf(acc[i][1]);
            pk[2] = (short)f2bf(acc[i][2]); pk[3] = (short)f2bf(acc[i][3]);
            *(short4v*)&vb[((size_t)bh * 64 + ty * 4 + i) * HW + p0 + tx * 4] = pk;
        }
    } else {
        // Q/K: p-major [bh][p][dd]; Q pre-scaled by 1/8
        const float s = (which == 0) ? 0.125f : 1.0f;
        unsigned short* dst = (which == 0) ? qb : kb;
        #pragma unroll
        for (int j = 0; j < 4; ++j) {
            short4v pk;
            pk[0] = (short)f2bf(acc[0][j] * s); pk[1] = (short)f2bf(acc[1][j] * s);
            pk[2] = (short)f2bf(acc[2][j] * s); pk[3] = (short)f2bf(acc[3][j] * s);
            *(short4v*)&dst[((size_t)bh * HW + p0 + tx * 4 + j) * 64 + ty * 4] = pk;
        }
    }
}

// ---------------------------------------------------------------------------
// Kernel 2: MFMA flash attention.
// Block = 4 waves, 128 q rows (32/wave as 2 col-tiles of 16). KV-tile = 64.
// S^T = K·Q^T (16x16x32 bf16 MFMA), softmax in-register (lane owns one q),
// P staged through per-wave LDS, O^T = V^T·P^T. XOR-swizzled K/V tiles.
// ---------------------------------------------------------------------------
__global__ __launch_bounds__(256) void flash_mfma_k(
    const unsigned short* __restrict__ qb, const unsigned short* __restrict__ kb,
    const unsigned short* __restrict__ vb, float* __restrict__ o)
{
    const int i0   = blockIdx.x * 128;
    const int bh   = blockIdx.y;
    const int t    = threadIdx.x;
    const int wid  = t >> 6;
    const int lane = t & 63;
    const int g    = lane >> 4, li = lane & 15;

    const unsigned short* qg = qb + (size_t)bh * HW * 64;
    const unsigned short* kg = kb + (size_t)bh * HW * 64;
    const unsigned short* vg = vb + (size_t)bh * 64 * HW;
    float*                og = o  + (size_t)bh * 64 * HW;

    __shared__ char  klds[8192];            // [64 j][64 dd] bf16, byte^=(row&7)<<4
    __shared__ char  vlds[8192];            // [64 dd][64 j] bf16, same swizzle
    __shared__ short plds[4][32][72];       // per-wave P [q][j], pad 72

    // Q fragments (B-operand): lane holds Q[q=qt*16+li][dd = c*32+g*8 .. +8]
    short8v qf[2][2];
    #pragma unroll
    for (int qt = 0; qt < 2; ++qt)
        #pragma unroll
        for (int c = 0; c < 2; ++c) {
            const int q = i0 + wid * 32 + qt * 16 + li;
            qf[qt][c] = *(const short8v*)(qg + (size_t)q * 64 + c * 32 + g * 8);
        }

    float m[2] = {-1e30f, -1e30f};
    float l[2] = {0.f, 0.f};
    float4v acco[4][2];                      // O^T accs [dt][qt]
    #pragma unroll
    for (int dt = 0; dt < 4; ++dt)
        #pragma unroll
        for (int qt = 0; qt < 2; ++qt)
            acco[dt][qt] = (float4v){0.f, 0.f, 0.f, 0.f};

    for (int kt = 0; kt < 64; ++kt) {
        __syncthreads();
        // stage K-tile rows (j) and V-tile rows (dd), 16B/chunk, swizzled
        #pragma unroll
        for (int rep = 0; rep < 2; ++rep) {
            const int chunk = rep * 256 + t;
            const int row = chunk >> 3, c16 = chunk & 7;
            const int dsw = row * 128 + ((c16 * 16) ^ ((row & 7) << 4));
            *(float4*)(klds + dsw) =
                *(const float4*)((const char*)kg + (size_t)(kt * 64 + row) * 128 + c16 * 16);
            *(float4*)(vlds + dsw) =
                *(const float4*)((const char*)vg + (size_t)row * 8192 + kt * 128 + c16 * 16);
        }
        __syncthreads();

        // --- S^T = K · Q^T : D[j][q], 4 j-tiles x 2 q-tiles ---
        float4v accs[4][2];
        #pragma unroll
        for (int jt = 0; jt < 4; ++jt)
            #pragma unroll
            for (int qt = 0; qt < 2; ++qt)
                accs[jt][qt] = (float4v){0.f, 0.f, 0.f, 0.f};

        #pragma unroll
        for (int jt = 0; jt < 4; ++jt) {
            #pragma unroll
            for (int c = 0; c < 2; ++c) {
                const int row = jt * 16 + li;
                const short8v kf = *(const short8v*)(
                    klds + row * 128 + ((c * 64 + g * 16) ^ ((row & 7) << 4)));
                accs[jt][0] = __builtin_amdgcn_mfma_f32_16x16x32_bf16(kf, qf[0][c], accs[jt][0], 0, 0, 0);
                accs[jt][1] = __builtin_amdgcn_mfma_f32_16x16x32_bf16(kf, qf[1][c], accs[jt][1], 0, 0, 0);
            }
        }

        // --- online softmax (lane owns q = qt*16+li; j = 16*jt+4*g+r) ---
        #pragma unroll
        for (int qt = 0; qt < 2; ++qt) {
            float tmax = -1e30f;
            #pragma unroll
            for (int jt = 0; jt < 4; ++jt)
                #pragma unroll
                for (int r = 0; r < 4; ++r) tmax = fmaxf(tmax, accs[jt][qt][r]);
            tmax = fmaxf(tmax, __shfl_xor(tmax, 16, 64));
            tmax = fmaxf(tmax, __shfl_xor(tmax, 32, 64));
            const float mnew = fmaxf(m[qt], tmax);
            const float fsc  = __expf(m[qt] - mnew);
            m[qt] = mnew;
            float ls = 0.f;
            #pragma unroll
            for (int jt = 0; jt < 4; ++jt) {
                short4v pk;
                #pragma unroll
                for (int r = 0; r < 4; ++r) {
                    const float p = __expf(accs[jt][qt][r] - mnew);
                    ls += p;
                    pk[r] = (short)f2bf(p);
                }
                *(short4v*)&plds[wid][qt * 16 + li][jt * 16 + 4 * g] = pk;
            }
            l[qt] = l[qt] * fsc + ls;
            #pragma unroll
            for (int dt = 0; dt < 4; ++dt) {
                acco[dt][qt][0] *= fsc; acco[dt][qt][1] *= fsc;
                acco[dt][qt][2] *= fsc; acco[dt][qt][3] *= fsc;
            }
        }

        // --- PV: O^T += V^T · P^T ---
        short8v pf[2][2];
        #pragma unroll
        for (int qt = 0; qt < 2; ++qt)
            #pragma unroll
            for (int c = 0; c < 2; ++c)
                pf[qt][c] = *(const short8v*)(
                    (const char*)&plds[wid][qt * 16 + li][0] + c * 64 + g * 16);
        #pragma unroll
        for (int dt = 0; dt < 4; ++dt) {
            #pragma unroll
            for (int c = 0; c < 2; ++c) {
                const int row = dt * 16 + li;
                const short8v vf = *(const short8v*)(
                    vlds + row * 128 + ((c * 64 + g * 16) ^ ((row & 7) << 4)));
                acco[dt][0] = __builtin_amdgcn_mfma_f32_16x16x32_bf16(vf, pf[0][c], acco[dt][0], 0, 0, 0);
                acco[dt][1] = __builtin_amdgcn_mfma_f32_16x16x32_bf16(vf, pf[1][c], acco[dt][1], 0, 0, 0);
            }
        }
    }

    // epilogue: reduce l across g-groups, write O^T (= att [bh][dd][p] f32)
    #pragma unroll
    for (int qt = 0; qt < 2; ++qt) {
        float lt = l[qt];
        lt += __shfl_xor(lt, 16, 64);
        lt += __shfl_xor(lt, 32, 64);
        const float inv = 1.0f / lt;
        const int q = i0 + wid * 32 + qt * 16 + li;
        #pragma unroll
        for (int dt = 0; dt < 4; ++dt)
            #pragma unroll
            for (int r = 0; r < 4; ++r)
                og[(size_t)(dt * 16 + 4 * g + r) * HW + q] = acco[dt][qt][r] * inv;
    }
}

// ---------------------------------------------------------------------------
// Kernel 3: out = x + w_out @ att + b_out (fp32 VALU GEMM)
// ---------------------------------------------------------------------------
__global__ __launch_bounds__(256) void proj_gemm_k(
    const float* __restrict__ att, const float* __restrict__ w,
    const float* __restrict__ bias, const float* __restrict__ x,
    float* __restrict__ out)
{
    const int o0 = blockIdx.x * 64;
    const int p0 = blockIdx.y * 64;
    const int b  = blockIdx.z;
    const int t  = threadIdx.x;
    const int tx = t & 15, ty = t >> 4;

    __shared__ float wt[64 * 65];
    __shared__ float xs[64 * 64];

    float acc[4][4] = {};
    const float* ab = att + (size_t)b * CIN * HW;

    for (int kc = 0; kc < 4; ++kc) {
        __syncthreads();
        for (int iter = 0; iter < 4; ++iter) {
            int idx = iter * 1024 + t * 4;
            int oo = idx >> 6, cc = idx & 63;
            const float4 wv = *(const float4*)&w[(o0 + oo) * CIN + kc * 64 + cc];
            wt[(cc + 0) * 65 + oo] = wv.x;
            wt[(cc + 1) * 65 + oo] = wv.y;
            wt[(cc + 2) * 65 + oo] = wv.z;
            wt[(cc + 3) * 65 + oo] = wv.w;
        }
        for (int iter = 0; iter < 4; ++iter) {
            int idx = iter * 1024 + t * 4;
            int cc = idx >> 6, pp = idx & 63;
            *(float4*)&xs[idx] = *(const float4*)&ab[(size_t)(kc * 64 + cc) * HW + p0 + pp];
        }
        __syncthreads();

        #pragma unroll 8
        for (int cc = 0; cc < 64; ++cc) {
            const float w0 = wt[cc * 65 + ty * 4 + 0];
            const float w1 = wt[cc * 65 + ty * 4 + 1];
            const float w2 = wt[cc * 65 + ty * 4 + 2];
            const float w3 = wt[cc * 65 + ty * 4 + 3];
            const float4 xv = *(const float4*)&xs[cc * 64 + tx * 4];
            acc[0][0] += w0 * xv.x; acc[0][1] += w0 * xv.y; acc[0][2] += w0 * xv.z; acc[0][3] += w0 * xv.w;
            acc[1][0] += w1 * xv.x; acc[1][1] += w1 * xv.y; acc[1][2] += w1 * xv.z; acc[1][3] += w1 * xv.w;
            acc[2][0] += w2 * xv.x; acc[2][1] += w2 * xv.y; acc[2][2] += w2 * xv.z; acc[2][3] += w2 * xv.w;
            acc[3][0] += w3 * xv.x; acc[3][1] += w3 * xv.y; acc[3][2] += w3 * xv.z; acc[3][3] += w3 * xv.w;
        }
    }

    #pragma unroll
    for (int i = 0; i < 4; ++i) {
        const int oo = o0 + ty * 4 + i;
        const float bo = bias[oo];
        const size_t base = (size_t)(b * CIN + oo) * HW + p0 + tx * 4;
        const float4 xv = *(const float4*)&x[base];
        float4 val;
        val.x = acc[i][0] + bo + xv.x;
        val.y = acc[i][1] + bo + xv.y;
        val.z = acc[i][2] + bo + xv.z;
        val.w = acc[i][3] + bo + xv.w;
        *(float4*)&out[base] = val;
    }
}

extern "C" void kernel_launch(void* const* d_in, const int* in_sizes, int n_in,
                              void* d_out, int out_size, void* d_ws, size_t ws_size,
                              hipStream_t stream)
{
    const float* x     = (const float*)d_in[0];
    const float* w_qkv = (const float*)d_in[1];
    const float* w_out = (const float*)d_in[2];
    const float* b_out = (const float*)d_in[3];
    float* out = (float*)d_out;

    char* ws = (char*)d_ws;
    const size_t PLANE_BF = (size_t)16 * HW * 64 * sizeof(unsigned short); // 8 MB
    unsigned short* qb = (unsigned short*)(ws);
    unsigned short* kb = (unsigned short*)(ws + PLANE_BF);
    unsigned short* vb = (unsigned short*)(ws + 2 * PLANE_BF);
    float*          att = (float*)(ws + 3 * PLANE_BF);

    qkv_gemm_k<<<dim3(12, 64, 4), 256, 0, stream>>>(x, w_qkv, qb, kb, vb);
    flash_mfma_k<<<dim3(32, 16), 256, 0, stream>>>(qb, kb, vb, att);
    proj_gemm_k<<<dim3(4, 64, 4), 256, 0, stream>>>(att, w_out, b_out, x, out);
}

// Round 3
// 200.879 us; speedup vs baseline: 13.6449x; 1.3361x over previous
//
#include <hip/hip_runtime.h>

// AttentionBlock: x(4,256,64,64) fp32
//   qkv = w_qkv(768,256) @ x ; flash attention (heads=4, d=64, N=4096, 16 bh);
//   out = x + w_out @ att + b_out
// All matmuls on bf16 MFMA (fp32 accum). Softmax in exp2 domain (Q rows of
// w_qkv pre-scaled by 0.125*log2e at cast time).
//
// ws (bytes):
//   xt   [4][4096][256] bf16   @ 0        (8 MB)  x transposed p-major
//   qb   [16][4096][64] bf16   @ 8 MB     (Q, p-major, log2-scaled)
//   kb   [16][4096][64] bf16   @ 16 MB
//   vb   [16][64][4096] bf16   @ 24 MB    (V, d-major)
//   att  [4][4096][256] bf16   @ 32 MB    (O, p-major)
//   wqb  [768][256] bf16       @ 40 MB
//   wob  [256][256] bf16       @ 40 MB + 384 KB

#define HW 4096
#define CIN 256
#define LOG2E_DIV8 0.18033688011112042f

typedef __attribute__((ext_vector_type(8))) short short8v;
typedef __attribute__((ext_vector_type(4))) short short4v;
typedef __attribute__((ext_vector_type(4))) float float4v;

static __device__ __forceinline__ unsigned short f2bf(float f) {
    unsigned int u = __float_as_uint(f);
    u += 0x7fff + ((u >> 16) & 1);   // RNE
    return (unsigned short)(u >> 16);
}

// ---------------------------------------------------------------------------
// cast weights -> bf16 (Q rows of w_qkv pre-scaled into exp2 domain)
// ---------------------------------------------------------------------------
__global__ __launch_bounds__(256) void cast_w_k(
    const float* __restrict__ w_qkv, const float* __restrict__ w_out,
    unsigned short* __restrict__ wqb, unsigned short* __restrict__ wob)
{
    const int bi = blockIdx.x;
    if (bi < 192) {                       // w_qkv: 768*256 = 192 blocks * 1024
        const int idx = bi * 1024 + threadIdx.x * 4;
        const float s = (idx < 256 * 256) ? LOG2E_DIV8 : 1.0f;  // Q rows
        const float4 v = *(const float4*)&w_qkv[idx];
        short4v pk;
        pk[0] = (short)f2bf(v.x * s); pk[1] = (short)f2bf(v.y * s);
        pk[2] = (short)f2bf(v.z * s); pk[3] = (short)f2bf(v.w * s);
        *(short4v*)&wqb[idx] = pk;
    } else {                              // w_out: 256*256 = 64 blocks
        const int idx = (bi - 192) * 1024 + threadIdx.x * 4;
        const float4 v = *(const float4*)&w_out[idx];
        short4v pk;
        pk[0] = (short)f2bf(v.x); pk[1] = (short)f2bf(v.y);
        pk[2] = (short)f2bf(v.z); pk[3] = (short)f2bf(v.w);
        *(short4v*)&wob[idx] = pk;
    }
}

// ---------------------------------------------------------------------------
// cast + transpose x: [b][c][p] f32 -> xt [b][p][c] bf16 (64x64 LDS tiles)
// ---------------------------------------------------------------------------
__global__ __launch_bounds__(256) void cast_x_k(
    const float* __restrict__ x, unsigned short* __restrict__ xt)
{
    const int p0 = blockIdx.x * 64, c0 = blockIdx.y * 64, b = blockIdx.z;
    const int t = threadIdx.x;
    __shared__ float tile[64][65];

    const float* xb = x + ((size_t)b * CIN + c0) * HW + p0;
    #pragma unroll
    for (int iter = 0; iter < 4; ++iter) {
        const int idx = iter * 1024 + t * 4;
        const int cc = idx >> 6, pp = idx & 63;
        const float4 v = *(const float4*)&xb[(size_t)cc * HW + pp];
        tile[cc][pp + 0] = v.x; tile[cc][pp + 1] = v.y;
        tile[cc][pp + 2] = v.z; tile[cc][pp + 3] = v.w;
    }
    __syncthreads();
    unsigned short* xo = xt + ((size_t)b * HW + p0) * CIN + c0;
    #pragma unroll
    for (int iter = 0; iter < 4; ++iter) {
        const int idx = iter * 1024 + t * 4;
        const int pp = idx >> 6, cc = idx & 63;
        short4v pk;
        pk[0] = (short)f2bf(tile[cc + 0][pp]); pk[1] = (short)f2bf(tile[cc + 1][pp]);
        pk[2] = (short)f2bf(tile[cc + 2][pp]); pk[3] = (short)f2bf(tile[cc + 3][pp]);
        *(short4v*)&xo[(size_t)pp * CIN + cc] = pk;
    }
}

// ---------------------------------------------------------------------------
// qkv projection, bf16 MFMA. C[o,p] = sum_c W[o,c] * Xt[p,c], 128x128 tile,
// 4 waves (2x2 of 64x64), BK=64, XOR-swizzled LDS, reg-prefetch staging.
// Epilogue scatters bf16 into qb/kb (p-major) or vb (d-major).
// ---------------------------------------------------------------------------
__global__ __launch_bounds__(256) void qkv_mfma_k(
    const unsigned short* __restrict__ wqb, const unsigned short* __restrict__ xt,
    unsigned short* __restrict__ qb, unsigned short* __restrict__ kb,
    unsigned short* __restrict__ vb)
{
    const int o0 = blockIdx.x * 128;      // 6
    const int p0 = blockIdx.y * 128;      // 32
    const int b  = blockIdx.z;
    const int t = threadIdx.x;
    const int wid = t >> 6, lane = t & 63, g = lane >> 4, li = lane & 15;
    const int wo = (wid >> 1) * 64, wp = (wid & 1) * 64;

    __shared__ char alds[16384];          // W  [128 o][64 c] bf16, swizzled
    __shared__ char blds[16384];          // Xt [128 p][64 c] bf16, swizzled

    const int srow8 = t >> 3, sc16 = t & 7;
    const char* asrc = (const char*)wqb + ((size_t)(o0 + srow8) * 256) * 2 + sc16 * 16;
    const char* bsrc = (const char*)xt + (((size_t)b * HW + p0 + srow8) * 256) * 2 + sc16 * 16;

    float4 areg[4], breg[4];
    #pragma unroll
    for (int it = 0; it < 4; ++it) {
        areg[it] = *(const float4*)(asrc + (size_t)it * 32 * 512);
        breg[it] = *(const float4*)(bsrc + (size_t)it * 32 * 512);
    }

    float4v acc[4][4];
    #pragma unroll
    for (int mt = 0; mt < 4; ++mt)
        #pragma unroll
        for (int nt = 0; nt < 4; ++nt) acc[mt][nt] = (float4v){0.f, 0.f, 0.f, 0.f};

    for (int ks = 0; ks < 4; ++ks) {
        #pragma unroll
        for (int it = 0; it < 4; ++it) {
            const int row = it * 32 + srow8;
            const int dsw = row * 128 + ((sc16 * 16) ^ ((row & 7) << 4));
            *(float4*)(alds + dsw) = areg[it];
            *(float4*)(blds + dsw) = breg[it];
        }
        __syncthreads();
        if (ks < 3) {
            #pragma unroll
            for (int it = 0; it < 4; ++it) {
                areg[it] = *(const float4*)(asrc + (size_t)it * 32 * 512 + (ks + 1) * 128);
                breg[it] = *(const float4*)(bsrc + (size_t)it * 32 * 512 + (ks + 1) * 128);
            }
        }
        short8v af[4][2], bf[4][2];
        #pragma unroll
        for (int mt = 0; mt < 4; ++mt) {
            const int row = wo + mt * 16 + li;
            #pragma unroll
            for (int kc = 0; kc < 2; ++kc)
                af[mt][kc] = *(const short8v*)(alds + row * 128 + ((kc * 64 + g * 16) ^ ((row & 7) << 4)));
        }
        #pragma unroll
        for (int nt = 0; nt < 4; ++nt) {
            const int row = wp + nt * 16 + li;
            #pragma unroll
            for (int kc = 0; kc < 2; ++kc)
                bf[nt][kc] = *(const short8v*)(blds + row * 128 + ((kc * 64 + g * 16) ^ ((row & 7) << 4)));
        }
        #pragma unroll
        for (int mt = 0; mt < 4; ++mt)
            #pragma unroll
            for (int nt = 0; nt < 4; ++nt) {
                acc[mt][nt] = __builtin_amdgcn_mfma_f32_16x16x32_bf16(af[mt][0], bf[nt][0], acc[mt][nt], 0, 0, 0);
                acc[mt][nt] = __builtin_amdgcn_mfma_f32_16x16x32_bf16(af[mt][1], bf[nt][1], acc[mt][nt], 0, 0, 0);
            }
        __syncthreads();
    }

    const int which = o0 >> 8;            // 0=Q 1=K 2=V
    #pragma unroll
    for (int mt = 0; mt < 4; ++mt) {
        const int o_b = o0 + wo + mt * 16 + g * 4;
        const int head = (o_b >> 6) & 3;
        const int dd = o_b & 63;
        const int bh = b * 4 + head;
        if (which < 2) {
            unsigned short* dst = which ? kb : qb;
            #pragma unroll
            for (int nt = 0; nt < 4; ++nt) {
                const int p = p0 + wp + nt * 16 + li;
                short4v pk;
                #pragma unroll
                for (int r = 0; r < 4; ++r) pk[r] = (short)f2bf(acc[mt][nt][r]);
                *(short4v*)&dst[((size_t)bh * HW + p) * 64 + dd] = pk;
            }
        } else {
            #pragma unroll
            for (int nt = 0; nt < 4; ++nt) {
                const int p = p0 + wp + nt * 16 + li;
                #pragma unroll
                for (int r = 0; r < 4; ++r)
                    vb[((size_t)bh * 64 + dd + r) * HW + p] = f2bf(acc[mt][nt][r]);
            }
        }
    }
}

// ---------------------------------------------------------------------------
// flash attention: 512 threads = 8 waves x 16 q-rows; KV-tile 64.
// S^T = K·Q^T (exp2 domain), defer-max (thr 8), P via per-wave LDS,
// O^T = V^T·P^T. Reg-prefetched K/V staging. Output bf16 att [b][p][c].
// ---------------------------------------------------------------------------
__global__ __launch_bounds__(512) void flash_mfma_k(
    const unsigned short* __restrict__ qb, const unsigned short* __restrict__ kb,
    const unsigned short* __restrict__ vb, unsigned short* __restrict__ att)
{
    const int i0 = blockIdx.x * 128;      // 32
    const int bh = blockIdx.y;            // 16
    const int t = threadIdx.x;
    const int wid = t >> 6, lane = t & 63, g = lane >> 4, li = lane & 15;
    const int b = bh >> 2, head = bh & 3;

    const unsigned short* qg = qb + (size_t)bh * HW * 64;
    const unsigned short* kg = kb + (size_t)bh * HW * 64;
    const unsigned short* vg = vb + (size_t)bh * 64 * HW;

    __shared__ char klds[8192];           // [64 j][64 d] swizzled
    __shared__ char vlds[8192];           // [64 d][64 j] swizzled
    __shared__ short plds[8][16][72];     // per-wave P [q][j]

    const int q = i0 + wid * 16 + li;
    short8v qf[2];
    #pragma unroll
    for (int c = 0; c < 2; ++c)
        qf[c] = *(const short8v*)(qg + (size_t)q * 64 + c * 32 + g * 8);

    float m = -1e30f, l = 0.0f;
    float4v acco[4];
    #pragma unroll
    for (int dt = 0; dt < 4; ++dt) acco[dt] = (float4v){0.f, 0.f, 0.f, 0.f};

    const int srow = t >> 3, sc16 = t & 7;
    const int dsw = srow * 128 + ((sc16 * 16) ^ ((srow & 7) << 4));
    const char* ksrc = (const char*)kg + (size_t)srow * 128 + sc16 * 16;
    const char* vsrc = (const char*)vg + (size_t)srow * 8192 + sc16 * 16;

    float4 kreg = *(const float4*)ksrc;
    float4 vreg = *(const float4*)vsrc;

    for (int kt = 0; kt < 64; ++kt) {
        *(float4*)(klds + dsw) = kreg;
        *(float4*)(vlds + dsw) = vreg;
        __syncthreads();
        if (kt < 63) {
            kreg = *(const float4*)(ksrc + (size_t)(kt + 1) * 8192);
            vreg = *(const float4*)(vsrc + (size_t)(kt + 1) * 128);
        }

        // --- S^T = K · Q^T ---
        float4v accs[4];
        #pragma unroll
        for (int jt = 0; jt < 4; ++jt) accs[jt] = (float4v){0.f, 0.f, 0.f, 0.f};
        #pragma unroll
        for (int jt = 0; jt < 4; ++jt) {
            const int row = jt * 16 + li;
            #pragma unroll
            for (int c = 0; c < 2; ++c) {
                const short8v kf = *(const short8v*)(klds + row * 128 + ((c * 64 + g * 16) ^ ((row & 7) << 4)));
                accs[jt] = __builtin_amdgcn_mfma_f32_16x16x32_bf16(kf, qf[c], accs[jt], 0, 0, 0);
            }
        }

        // --- online softmax, exp2 domain, defer-max ---
        float t0 = fmaxf(fmaxf(accs[0][0], accs[0][1]), fmaxf(accs[0][2], accs[0][3]));
        float t1 = fmaxf(fmaxf(accs[1][0], accs[1][1]), fmaxf(accs[1][2], accs[1][3]));
        float t2 = fmaxf(fmaxf(accs[2][0], accs[2][1]), fmaxf(accs[2][2], accs[2][3]));
        float t3 = fmaxf(fmaxf(accs[3][0], accs[3][1]), fmaxf(accs[3][2], accs[3][3]));
        float tmax = fmaxf(fmaxf(t0, t1), fmaxf(t2, t3));
        tmax = fmaxf(tmax, __shfl_xor(tmax, 16, 64));
        tmax = fmaxf(tmax, __shfl_xor(tmax, 32, 64));
        if (__any(tmax > m + 8.0f)) {
            const float mnew = fmaxf(m, tmax);
            const float fsc = exp2f(m - mnew);
            m = mnew;
            l *= fsc;
            #pragma unroll
            for (int dt = 0; dt < 4; ++dt) {
                acco[dt][0] *= fsc; acco[dt][1] *= fsc;
                acco[dt][2] *= fsc; acco[dt][3] *= fsc;
            }
        }
        float ls = 0.f;
        #pragma unroll
        for (int jt = 0; jt < 4; ++jt) {
            short4v pk;
            #pragma unroll
            for (int r = 0; r < 4; ++r) {
                const float p = exp2f(accs[jt][r] - m);
                ls += p;
                pk[r] = (short)f2bf(p);
            }
            *(short4v*)&plds[wid][li][jt * 16 + 4 * g] = pk;
        }
        l += ls;

        // --- PV: O^T += V^T · P^T ---
        short8v pf[2];
        #pragma unroll
        for (int c = 0; c < 2; ++c)
            pf[c] = *(const short8v*)((const char*)&plds[wid][li][0] + c * 64 + g * 16);
        #pragma unroll
        for (int dt = 0; dt < 4; ++dt) {
            const int row = dt * 16 + li;
            #pragma unroll
            for (int c = 0; c < 2; ++c) {
                const short8v vf = *(const short8v*)(vlds + row * 128 + ((c * 64 + g * 16) ^ ((row & 7) << 4)));
                acco[dt] = __builtin_amdgcn_mfma_f32_16x16x32_bf16(vf, pf[c], acco[dt], 0, 0, 0);
            }
        }
        __syncthreads();
    }

    float lt = l;
    lt += __shfl_xor(lt, 16, 64);
    lt += __shfl_xor(lt, 32, 64);
    const float inv = 1.0f / lt;
    #pragma unroll
    for (int dt = 0; dt < 4; ++dt) {
        short4v pk;
        #pragma unroll
        for (int r = 0; r < 4; ++r) pk[r] = (short)f2bf(acco[dt][r] * inv);
        *(short4v*)&att[((size_t)b * HW + q) * CIN + head * 64 + dt * 16 + 4 * g] = pk;
    }
}

// ---------------------------------------------------------------------------
// output projection, bf16 MFMA + bias + residual (fp32 out).
// ---------------------------------------------------------------------------
__global__ __launch_bounds__(256) void proj_mfma_k(
    const unsigned short* __restrict__ wob, const unsigned short* __restrict__ att,
    const float* __restrict__ bias, const float* __restrict__ x,
    float* __restrict__ out)
{
    const int o0 = blockIdx.x * 128;      // 2
    const int p0 = blockIdx.y * 128;      // 32
    const int b  = blockIdx.z;
    const int t = threadIdx.x;
    const int wid = t >> 6, lane = t & 63, g = lane >> 4, li = lane & 15;
    const int wo = (wid >> 1) * 64, wp = (wid & 1) * 64;

    __shared__ char alds[16384];
    __shared__ char blds[16384];

    const int srow8 = t >> 3, sc16 = t & 7;
    const char* asrc = (const char*)wob + ((size_t)(o0 + srow8) * 256) * 2 + sc16 * 16;
    const char* bsrc = (const char*)att + (((size_t)b * HW + p0 + srow8) * 256) * 2 + sc16 * 16;

    float4 areg[4], breg[4];
    #pragma unroll
    for (int it = 0; it < 4; ++it) {
        areg[it] = *(const float4*)(asrc + (size_t)it * 32 * 512);
        breg[it] = *(const float4*)(bsrc + (size_t)it * 32 * 512);
    }

    float4v acc[4][4];
    #pragma unroll
    for (int mt = 0; mt < 4; ++mt)
        #pragma unroll
        for (int nt = 0; nt < 4; ++nt) acc[mt][nt] = (float4v){0.f, 0.f, 0.f, 0.f};

    for (int ks = 0; ks < 4; ++ks) {
        #pragma unroll
        for (int it = 0; it < 4; ++it) {
            const int row = it * 32 + srow8;
            const int dsw = row * 128 + ((sc16 * 16) ^ ((row & 7) << 4));
            *(float4*)(alds + dsw) = areg[it];
            *(float4*)(blds + dsw) = breg[it];
        }
        __syncthreads();
        if (ks < 3) {
            #pragma unroll
            for (int it = 0; it < 4; ++it) {
                areg[it] = *(const float4*)(asrc + (size_t)it * 32 * 512 + (ks + 1) * 128);
                breg[it] = *(const float4*)(bsrc + (size_t)it * 32 * 512 + (ks + 1) * 128);
            }
        }
        short8v af[4][2], bf[4][2];
        #pragma unroll
        for (int mt = 0; mt < 4; ++mt) {
            const int row = wo + mt * 16 + li;
            #pragma unroll
            for (int kc = 0; kc < 2; ++kc)
                af[mt][kc] = *(const short8v*)(alds + row * 128 + ((kc * 64 + g * 16) ^ ((row & 7) << 4)));
        }
        #pragma unroll
        for (int nt = 0; nt < 4; ++nt) {
            const int row = wp + nt * 16 + li;
            #pragma unroll
            for (int kc = 0; kc < 2; ++kc)
                bf[nt][kc] = *(const short8v*)(blds + row * 128 + ((kc * 64 + g * 16) ^ ((row & 7) << 4)));
        }
        #pragma unroll
        for (int mt = 0; mt < 4; ++mt)
            #pragma unroll
            for (int nt = 0; nt < 4; ++nt) {
                acc[mt][nt] = __builtin_amdgcn_mfma_f32_16x16x32_bf16(af[mt][0], bf[nt][0], acc[mt][nt], 0, 0, 0);
                acc[mt][nt] = __builtin_amdgcn_mfma_f32_16x16x32_bf16(af[mt][1], bf[nt][1], acc[mt][nt], 0, 0, 0);
            }
        __syncthreads();
    }

    #pragma unroll
    for (int mt = 0; mt < 4; ++mt) {
        const int o_b = o0 + wo + mt * 16 + g * 4;
        #pragma unroll
        for (int nt = 0; nt < 4; ++nt) {
            const int p = p0 + wp + nt * 16 + li;
            #pragma unroll
            for (int r = 0; r < 4; ++r) {
                const int o = o_b + r;
                const size_t ix = ((size_t)b * CIN + o) * HW + p;
                out[ix] = acc[mt][nt][r] + bias[o] + x[ix];
            }
        }
    }
}

extern "C" void kernel_launch(void* const* d_in, const int* in_sizes, int n_in,
                              void* d_out, int out_size, void* d_ws, size_t ws_size,
                              hipStream_t stream)
{
    const float* x     = (const float*)d_in[0];
    const float* w_qkv = (const float*)d_in[1];
    const float* w_out = (const float*)d_in[2];
    const float* b_out = (const float*)d_in[3];
    float* out = (float*)d_out;

    char* ws = (char*)d_ws;
    const size_t MB = 1024 * 1024;
    unsigned short* xt  = (unsigned short*)(ws);
    unsigned short* qb  = (unsigned short*)(ws + 8 * MB);
    unsigned short* kb  = (unsigned short*)(ws + 16 * MB);
    unsigned short* vb  = (unsigned short*)(ws + 24 * MB);
    unsigned short* att = (unsigned short*)(ws + 32 * MB);
    unsigned short* wqb = (unsigned short*)(ws + 40 * MB);
    unsigned short* wob = (unsigned short*)(ws + 40 * MB + 768 * 256 * 2);

    cast_w_k<<<256, 256, 0, stream>>>(w_qkv, w_out, wqb, wob);
    cast_x_k<<<dim3(64, 4, 4), 256, 0, stream>>>(x, xt);
    qkv_mfma_k<<<dim3(6, 32, 4), 256, 0, stream>>>(wqb, xt, qb, kb, vb);
    flash_mfma_k<<<dim3(32, 16), 512, 0, stream>>>(qb, kb, vb, att);
    proj_mfma_k<<<dim3(2, 32, 4), 256, 0, stream>>>(wob, att, b_out, x, out);
}

// Round 4
// 198.689 us; speedup vs baseline: 13.7953x; 1.0110x over previous
//
#include <hip/hip_runtime.h>

// AttentionBlock: x(4,256,64,64) fp32
//   qkv = w_qkv(768,256) @ x ; flash attention (heads=4, d=64, N=4096, 16 bh);
//   out = x + w_out @ att + b_out
// All matmuls bf16 MFMA (fp32 accum). Softmax in exp2 domain (Q rows of
// w_qkv pre-scaled by 0.125*log2e at cast time). bf16 packing via
// v_cvt_pk_bf16_f32.
//
// ws: xt[4][4096][256]bf16 @0 | qb[16][4096][64] @8M | kb @16M |
//     vb[16][64][4096] @24M | att[4][4096][256] @32M | wqb @40M | wob after.

#define HW 4096
#define CIN 256
#define LOG2E_DIV8 0.18033688011112042f

typedef __attribute__((ext_vector_type(8))) short short8v;
typedef __attribute__((ext_vector_type(4))) short short4v;
typedef __attribute__((ext_vector_type(4))) float float4v;

static __device__ __forceinline__ unsigned short f2bf(float f) {
    unsigned int u = __float_as_uint(f);
    u += 0x7fff + ((u >> 16) & 1);   // RNE
    return (unsigned short)(u >> 16);
}
// packed f32x2 -> bf16x2 (lo <- a, hi <- b), RNE
static __device__ __forceinline__ unsigned int pkbf(float a, float b) {
    unsigned int r;
    asm("v_cvt_pk_bf16_f32 %0, %1, %2" : "=v"(r) : "v"(a), "v"(b));
    return r;
}

// ---------------------------------------------------------------------------
__global__ __launch_bounds__(256) void cast_w_k(
    const float* __restrict__ w_qkv, const float* __restrict__ w_out,
    unsigned short* __restrict__ wqb, unsigned short* __restrict__ wob)
{
    const int bi = blockIdx.x;
    if (bi < 192) {
        const int idx = bi * 1024 + threadIdx.x * 4;
        const float s = (idx < 256 * 256) ? LOG2E_DIV8 : 1.0f;  // Q rows
        const float4 v = *(const float4*)&w_qkv[idx];
        uint2 pk;
        pk.x = pkbf(v.x * s, v.y * s);
        pk.y = pkbf(v.z * s, v.w * s);
        *(uint2*)&wqb[idx] = pk;
    } else {
        const int idx = (bi - 192) * 1024 + threadIdx.x * 4;
        const float4 v = *(const float4*)&w_out[idx];
        uint2 pk;
        pk.x = pkbf(v.x, v.y);
        pk.y = pkbf(v.z, v.w);
        *(uint2*)&wob[idx] = pk;
    }
}

// ---------------------------------------------------------------------------
// cast + transpose x: [b][c][p] f32 -> xt [b][p][c] bf16
// ---------------------------------------------------------------------------
__global__ __launch_bounds__(256) void cast_x_k(
    const float* __restrict__ x, unsigned short* __restrict__ xt)
{
    const int p0 = blockIdx.x * 64, c0 = blockIdx.y * 64, b = blockIdx.z;
    const int t = threadIdx.x;
    __shared__ float tile[64][65];

    const float* xb = x + ((size_t)b * CIN + c0) * HW + p0;
    #pragma unroll
    for (int iter = 0; iter < 4; ++iter) {
        const int idx = iter * 1024 + t * 4;
        const int cc = idx >> 6, pp = idx & 63;
        const float4 v = *(const float4*)&xb[(size_t)cc * HW + pp];
        tile[cc][pp + 0] = v.x; tile[cc][pp + 1] = v.y;
        tile[cc][pp + 2] = v.z; tile[cc][pp + 3] = v.w;
    }
    __syncthreads();
    unsigned short* xo = xt + ((size_t)b * HW + p0) * CIN + c0;
    #pragma unroll
    for (int iter = 0; iter < 4; ++iter) {
        const int idx = iter * 1024 + t * 4;
        const int pp = idx >> 6, cc = idx & 63;
        uint2 pk;
        pk.x = pkbf(tile[cc + 0][pp], tile[cc + 1][pp]);
        pk.y = pkbf(tile[cc + 2][pp], tile[cc + 3][pp]);
        *(uint2*)&xo[(size_t)pp * CIN + cc] = pk;
    }
}

// ---------------------------------------------------------------------------
// qkv projection, bf16 MFMA, 128x128 tile, 4 waves, BK=64, swizzled LDS.
// ---------------------------------------------------------------------------
__global__ __launch_bounds__(256) void qkv_mfma_k(
    const unsigned short* __restrict__ wqb, const unsigned short* __restrict__ xt,
    unsigned short* __restrict__ qb, unsigned short* __restrict__ kb,
    unsigned short* __restrict__ vb)
{
    const int o0 = blockIdx.x * 128;
    const int p0 = blockIdx.y * 128;
    const int b  = blockIdx.z;
    const int t = threadIdx.x;
    const int wid = t >> 6, lane = t & 63, g = lane >> 4, li = lane & 15;
    const int wo = (wid >> 1) * 64, wp = (wid & 1) * 64;

    __shared__ char alds[16384];
    __shared__ char blds[16384];

    const int srow8 = t >> 3, sc16 = t & 7;
    const char* asrc = (const char*)wqb + ((size_t)(o0 + srow8) * 256) * 2 + sc16 * 16;
    const char* bsrc = (const char*)xt + (((size_t)b * HW + p0 + srow8) * 256) * 2 + sc16 * 16;

    float4 areg[4], breg[4];
    #pragma unroll
    for (int it = 0; it < 4; ++it) {
        areg[it] = *(const float4*)(asrc + (size_t)it * 32 * 512);
        breg[it] = *(const float4*)(bsrc + (size_t)it * 32 * 512);
    }

    float4v acc[4][4];
    #pragma unroll
    for (int mt = 0; mt < 4; ++mt)
        #pragma unroll
        for (int nt = 0; nt < 4; ++nt) acc[mt][nt] = (float4v){0.f, 0.f, 0.f, 0.f};

    for (int ks = 0; ks < 4; ++ks) {
        #pragma unroll
        for (int it = 0; it < 4; ++it) {
            const int row = it * 32 + srow8;
            const int dsw = row * 128 + ((sc16 * 16) ^ ((row & 7) << 4));
            *(float4*)(alds + dsw) = areg[it];
            *(float4*)(blds + dsw) = breg[it];
        }
        __syncthreads();
        if (ks < 3) {
            #pragma unroll
            for (int it = 0; it < 4; ++it) {
                areg[it] = *(const float4*)(asrc + (size_t)it * 32 * 512 + (ks + 1) * 128);
                breg[it] = *(const float4*)(bsrc + (size_t)it * 32 * 512 + (ks + 1) * 128);
            }
        }
        short8v af[4][2], bf[4][2];
        #pragma unroll
        for (int mt = 0; mt < 4; ++mt) {
            const int row = wo + mt * 16 + li;
            #pragma unroll
            for (int kc = 0; kc < 2; ++kc)
                af[mt][kc] = *(const short8v*)(alds + row * 128 + ((kc * 64 + g * 16) ^ ((row & 7) << 4)));
        }
        #pragma unroll
        for (int nt = 0; nt < 4; ++nt) {
            const int row = wp + nt * 16 + li;
            #pragma unroll
            for (int kc = 0; kc < 2; ++kc)
                bf[nt][kc] = *(const short8v*)(blds + row * 128 + ((kc * 64 + g * 16) ^ ((row & 7) << 4)));
        }
        #pragma unroll
        for (int mt = 0; mt < 4; ++mt)
            #pragma unroll
            for (int nt = 0; nt < 4; ++nt) {
                acc[mt][nt] = __builtin_amdgcn_mfma_f32_16x16x32_bf16(af[mt][0], bf[nt][0], acc[mt][nt], 0, 0, 0);
                acc[mt][nt] = __builtin_amdgcn_mfma_f32_16x16x32_bf16(af[mt][1], bf[nt][1], acc[mt][nt], 0, 0, 0);
            }
        __syncthreads();
    }

    const int which = o0 >> 8;            // 0=Q 1=K 2=V
    #pragma unroll
    for (int mt = 0; mt < 4; ++mt) {
        const int o_b = o0 + wo + mt * 16 + g * 4;
        const int head = (o_b >> 6) & 3;
        const int dd = o_b & 63;
        const int bh = b * 4 + head;
        if (which < 2) {
            unsigned short* dst = which ? kb : qb;
            #pragma unroll
            for (int nt = 0; nt < 4; ++nt) {
                const int p = p0 + wp + nt * 16 + li;
                uint2 pk;
                pk.x = pkbf(acc[mt][nt][0], acc[mt][nt][1]);
                pk.y = pkbf(acc[mt][nt][2], acc[mt][nt][3]);
                *(uint2*)&dst[((size_t)bh * HW + p) * 64 + dd] = pk;
            }
        } else {
            #pragma unroll
            for (int nt = 0; nt < 4; ++nt) {
                const int p = p0 + wp + nt * 16 + li;
                #pragma unroll
                for (int r = 0; r < 4; ++r)
                    vb[((size_t)bh * 64 + dd + r) * HW + p] = f2bf(acc[mt][nt][r]);
            }
        }
    }
}

// ---------------------------------------------------------------------------
// flash attention: 256 threads = 4 waves x 32 q-rows (2 q-tiles); KV-tile 64.
// S^T = K·Q^T (exp2 domain), defer-max (thr 8), P packed via v_cvt_pk_bf16,
// O^T = V^T·P^T. K/V frag reads amortized over 2 q-tiles.
// ---------------------------------------------------------------------------
__global__ __launch_bounds__(256) void flash_mfma_k(
    const unsigned short* __restrict__ qb, const unsigned short* __restrict__ kb,
    const unsigned short* __restrict__ vb, unsigned short* __restrict__ att)
{
    const int i0 = blockIdx.x * 128;      // 32
    const int bh = blockIdx.y;            // 16
    const int t = threadIdx.x;
    const int wid = t >> 6, lane = t & 63, g = lane >> 4, li = lane & 15;
    const int b = bh >> 2, head = bh & 3;

    const unsigned short* qg = qb + (size_t)bh * HW * 64;
    const unsigned short* kg = kb + (size_t)bh * HW * 64;
    const unsigned short* vg = vb + (size_t)bh * 64 * HW;

    __shared__ char klds[8192];           // [64 j][64 d] swizzled
    __shared__ char vlds[8192];           // [64 d][64 j] swizzled
    __shared__ short plds[4][32][72];     // per-wave P [q][j]

    short8v qf[2][2];
    #pragma unroll
    for (int qt = 0; qt < 2; ++qt)
        #pragma unroll
        for (int c = 0; c < 2; ++c) {
            const int q = i0 + wid * 32 + qt * 16 + li;
            qf[qt][c] = *(const short8v*)(qg + (size_t)q * 64 + c * 32 + g * 8);
        }

    float m[2] = {-1e30f, -1e30f};
    float l[2] = {0.f, 0.f};
    float4v acco[4][2];
    #pragma unroll
    for (int dt = 0; dt < 4; ++dt)
        #pragma unroll
        for (int qt = 0; qt < 2; ++qt) acco[dt][qt] = (float4v){0.f, 0.f, 0.f, 0.f};

    // staging: 2 chunks/thread/buffer (8 KB per buffer, 256 threads)
    const int srow0 = t >> 3, sc0 = t & 7;           // chunks 0..255
    const int srow1 = (t + 256) >> 3, sc1 = t & 7;   // chunks 256..511
    const int dsw0 = srow0 * 128 + ((sc0 * 16) ^ ((srow0 & 7) << 4));
    const int dsw1 = srow1 * 128 + ((sc1 * 16) ^ ((srow1 & 7) << 4));
    const char* ksrc0 = (const char*)kg + (size_t)srow0 * 128 + sc0 * 16;
    const char* ksrc1 = (const char*)kg + (size_t)srow1 * 128 + sc1 * 16;
    const char* vsrc0 = (const char*)vg + (size_t)srow0 * 8192 + sc0 * 16;
    const char* vsrc1 = (const char*)vg + (size_t)srow1 * 8192 + sc1 * 16;

    float4 kreg0 = *(const float4*)ksrc0, kreg1 = *(const float4*)ksrc1;
    float4 vreg0 = *(const float4*)vsrc0, vreg1 = *(const float4*)vsrc1;

    for (int kt = 0; kt < 64; ++kt) {
        *(float4*)(klds + dsw0) = kreg0;
        *(float4*)(klds + dsw1) = kreg1;
        *(float4*)(vlds + dsw0) = vreg0;
        *(float4*)(vlds + dsw1) = vreg1;
        __syncthreads();
        if (kt < 63) {
            kreg0 = *(const float4*)(ksrc0 + (size_t)(kt + 1) * 8192);
            kreg1 = *(const float4*)(ksrc1 + (size_t)(kt + 1) * 8192);
            vreg0 = *(const float4*)(vsrc0 + (size_t)(kt + 1) * 128);
            vreg1 = *(const float4*)(vsrc1 + (size_t)(kt + 1) * 128);
        }

        // --- S^T = K · Q^T : kf read once, feeds both q-tiles ---
        float4v accs[4][2];
        #pragma unroll
        for (int jt = 0; jt < 4; ++jt)
            #pragma unroll
            for (int qt = 0; qt < 2; ++qt) accs[jt][qt] = (float4v){0.f, 0.f, 0.f, 0.f};
        #pragma unroll
        for (int jt = 0; jt < 4; ++jt) {
            const int row = jt * 16 + li;
            #pragma unroll
            for (int c = 0; c < 2; ++c) {
                const short8v kf = *(const short8v*)(klds + row * 128 + ((c * 64 + g * 16) ^ ((row & 7) << 4)));
                accs[jt][0] = __builtin_amdgcn_mfma_f32_16x16x32_bf16(kf, qf[0][c], accs[jt][0], 0, 0, 0);
                accs[jt][1] = __builtin_amdgcn_mfma_f32_16x16x32_bf16(kf, qf[1][c], accs[jt][1], 0, 0, 0);
            }
        }

        // --- online softmax, exp2 domain, defer-max ---
        float tmax[2];
        #pragma unroll
        for (int qt = 0; qt < 2; ++qt) {
            float t0 = fmaxf(fmaxf(accs[0][qt][0], accs[0][qt][1]), fmaxf(accs[0][qt][2], accs[0][qt][3]));
            float t1 = fmaxf(fmaxf(accs[1][qt][0], accs[1][qt][1]), fmaxf(accs[1][qt][2], accs[1][qt][3]));
            float t2 = fmaxf(fmaxf(accs[2][qt][0], accs[2][qt][1]), fmaxf(accs[2][qt][2], accs[2][qt][3]));
            float t3 = fmaxf(fmaxf(accs[3][qt][0], accs[3][qt][1]), fmaxf(accs[3][qt][2], accs[3][qt][3]));
            float tm = fmaxf(fmaxf(t0, t1), fmaxf(t2, t3));
            tm = fmaxf(tm, __shfl_xor(tm, 16, 64));
            tm = fmaxf(tm, __shfl_xor(tm, 32, 64));
            tmax[qt] = tm;
        }
        if (__any((tmax[0] > m[0] + 8.0f) || (tmax[1] > m[1] + 8.0f))) {
            #pragma unroll
            for (int qt = 0; qt < 2; ++qt) {
                const float mnew = fmaxf(m[qt], tmax[qt]);
                const float fsc = exp2f(m[qt] - mnew);
                m[qt] = mnew;
                l[qt] *= fsc;
                #pragma unroll
                for (int dt = 0; dt < 4; ++dt) {
                    acco[dt][qt][0] *= fsc; acco[dt][qt][1] *= fsc;
                    acco[dt][qt][2] *= fsc; acco[dt][qt][3] *= fsc;
                }
            }
        }
        #pragma unroll
        for (int qt = 0; qt < 2; ++qt) {
            float ls = 0.f;
            #pragma unroll
            for (int jt = 0; jt < 4; ++jt) {
                const float p0 = exp2f(accs[jt][qt][0] - m[qt]);
                const float p1 = exp2f(accs[jt][qt][1] - m[qt]);
                const float p2 = exp2f(accs[jt][qt][2] - m[qt]);
                const float p3 = exp2f(accs[jt][qt][3] - m[qt]);
                ls += (p0 + p1) + (p2 + p3);
                uint2 pk;
                pk.x = pkbf(p0, p1);
                pk.y = pkbf(p2, p3);
                *(uint2*)&plds[wid][qt * 16 + li][jt * 16 + 4 * g] = pk;
            }
            l[qt] += ls;
        }

        // --- PV: vf read once, feeds both q-tiles ---
        short8v pf[2][2];
        #pragma unroll
        for (int qt = 0; qt < 2; ++qt)
            #pragma unroll
            for (int c = 0; c < 2; ++c)
                pf[qt][c] = *(const short8v*)((const char*)&plds[wid][qt * 16 + li][0] + c * 64 + g * 16);
        #pragma unroll
        for (int dt = 0; dt < 4; ++dt) {
            const int row = dt * 16 + li;
            #pragma unroll
            for (int c = 0; c < 2; ++c) {
                const short8v vf = *(const short8v*)(vlds + row * 128 + ((c * 64 + g * 16) ^ ((row & 7) << 4)));
                acco[dt][0] = __builtin_amdgcn_mfma_f32_16x16x32_bf16(vf, pf[0][c], acco[dt][0], 0, 0, 0);
                acco[dt][1] = __builtin_amdgcn_mfma_f32_16x16x32_bf16(vf, pf[1][c], acco[dt][1], 0, 0, 0);
            }
        }
        __syncthreads();
    }

    #pragma unroll
    for (int qt = 0; qt < 2; ++qt) {
        float lt = l[qt];
        lt += __shfl_xor(lt, 16, 64);
        lt += __shfl_xor(lt, 32, 64);
        const float inv = 1.0f / lt;
        const int q = i0 + wid * 32 + qt * 16 + li;
        #pragma unroll
        for (int dt = 0; dt < 4; ++dt) {
            uint2 pk;
            pk.x = pkbf(acco[dt][qt][0] * inv, acco[dt][qt][1] * inv);
            pk.y = pkbf(acco[dt][qt][2] * inv, acco[dt][qt][3] * inv);
            *(uint2*)&att[((size_t)b * HW + q) * CIN + head * 64 + dt * 16 + 4 * g] = pk;
        }
    }
}

// ---------------------------------------------------------------------------
// output projection, bf16 MFMA + bias + residual (fp32 out).
// ---------------------------------------------------------------------------
__global__ __launch_bounds__(256) void proj_mfma_k(
    const unsigned short* __restrict__ wob, const unsigned short* __restrict__ att,
    const float* __restrict__ bias, const float* __restrict__ x,
    float* __restrict__ out)
{
    const int o0 = blockIdx.x * 128;
    const int p0 = blockIdx.y * 128;
    const int b  = blockIdx.z;
    const int t = threadIdx.x;
    const int wid = t >> 6, lane = t & 63, g = lane >> 4, li = lane & 15;
    const int wo = (wid >> 1) * 64, wp = (wid & 1) * 64;

    __shared__ char alds[16384];
    __shared__ char blds[16384];

    const int srow8 = t >> 3, sc16 = t & 7;
    const char* asrc = (const char*)wob + ((size_t)(o0 + srow8) * 256) * 2 + sc16 * 16;
    const char* bsrc = (const char*)att + (((size_t)b * HW + p0 + srow8) * 256) * 2 + sc16 * 16;

    float4 areg[4], breg[4];
    #pragma unroll
    for (int it = 0; it < 4; ++it) {
        areg[it] = *(const float4*)(asrc + (size_t)it * 32 * 512);
        breg[it] = *(const float4*)(bsrc + (size_t)it * 32 * 512);
    }

    float4v acc[4][4];
    #pragma unroll
    for (int mt = 0; mt < 4; ++mt)
        #pragma unroll
        for (int nt = 0; nt < 4; ++nt) acc[mt][nt] = (float4v){0.f, 0.f, 0.f, 0.f};

    for (int ks = 0; ks < 4; ++ks) {
        #pragma unroll
        for (int it = 0; it < 4; ++it) {
            const int row = it * 32 + srow8;
            const int dsw = row * 128 + ((sc16 * 16) ^ ((row & 7) << 4));
            *(float4*)(alds + dsw) = areg[it];
            *(float4*)(blds + dsw) = breg[it];
        }
        __syncthreads();
        if (ks < 3) {
            #pragma unroll
            for (int it = 0; it < 4; ++it) {
                areg[it] = *(const float4*)(asrc + (size_t)it * 32 * 512 + (ks + 1) * 128);
                breg[it] = *(const float4*)(bsrc + (size_t)it * 32 * 512 + (ks + 1) * 128);
            }
        }
        short8v af[4][2], bf[4][2];
        #pragma unroll
        for (int mt = 0; mt < 4; ++mt) {
            const int row = wo + mt * 16 + li;
            #pragma unroll
            for (int kc = 0; kc < 2; ++kc)
                af[mt][kc] = *(const short8v*)(alds + row * 128 + ((kc * 64 + g * 16) ^ ((row & 7) << 4)));
        }
        #pragma unroll
        for (int nt = 0; nt < 4; ++nt) {
            const int row = wp + nt * 16 + li;
            #pragma unroll
            for (int kc = 0; kc < 2; ++kc)
                bf[nt][kc] = *(const short8v*)(blds + row * 128 + ((kc * 64 + g * 16) ^ ((row & 7) << 4)));
        }
        #pragma unroll
        for (int mt = 0; mt < 4; ++mt)
            #pragma unroll
            for (int nt = 0; nt < 4; ++nt) {
                acc[mt][nt] = __builtin_amdgcn_mfma_f32_16x16x32_bf16(af[mt][0], bf[nt][0], acc[mt][nt], 0, 0, 0);
                acc[mt][nt] = __builtin_amdgcn_mfma_f32_16x16x32_bf16(af[mt][1], bf[nt][1], acc[mt][nt], 0, 0, 0);
            }
        __syncthreads();
    }

    #pragma unroll
    for (int mt = 0; mt < 4; ++mt) {
        const int o_b = o0 + wo + mt * 16 + g * 4;
        #pragma unroll
        for (int nt = 0; nt < 4; ++nt) {
            const int p = p0 + wp + nt * 16 + li;
            #pragma unroll
            for (int r = 0; r < 4; ++r) {
                const int o = o_b + r;
                const size_t ix = ((size_t)b * CIN + o) * HW + p;
                out[ix] = acc[mt][nt][r] + bias[o] + x[ix];
            }
        }
    }
}

extern "C" void kernel_launch(void* const* d_in, const int* in_sizes, int n_in,
                              void* d_out, int out_size, void* d_ws, size_t ws_size,
                              hipStream_t stream)
{
    const float* x     = (const float*)d_in[0];
    const float* w_qkv = (const float*)d_in[1];
    const float* w_out = (const float*)d_in[2];
    const float* b_out = (const float*)d_in[3];
    float* out = (float*)d_out;

    char* ws = (char*)d_ws;
    const size_t MB = 1024 * 1024;
    unsigned short* xt  = (unsigned short*)(ws);
    unsigned short* qb  = (unsigned short*)(ws + 8 * MB);
    unsigned short* kb  = (unsigned short*)(ws + 16 * MB);
    unsigned short* vb  = (unsigned short*)(ws + 24 * MB);
    unsigned short* att = (unsigned short*)(ws + 32 * MB);
    unsigned short* wqb = (unsigned short*)(ws + 40 * MB);
    unsigned short* wob = (unsigned short*)(ws + 40 * MB + 768 * 256 * 2);

    cast_w_k<<<256, 256, 0, stream>>>(w_qkv, w_out, wqb, wob);
    cast_x_k<<<dim3(64, 4, 4), 256, 0, stream>>>(x, xt);
    qkv_mfma_k<<<dim3(6, 32, 4), 256, 0, stream>>>(wqb, xt, qb, kb, vb);
    flash_mfma_k<<<dim3(32, 16), 256, 0, stream>>>(qb, kb, vb, att);
    proj_mfma_k<<<dim3(2, 32, 4), 256, 0, stream>>>(wob, att, b_out, x, out);
}

// Round 5
// 164.451 us; speedup vs baseline: 16.6675x; 1.2082x over previous
//
#include <hip/hip_runtime.h>

// AttentionBlock: x(4,256,64,64) fp32
//   qkv = w_qkv(768,256) @ x ; flash attention (heads=4, d=64, N=4096, 16 bh);
//   out = x + w_out @ att + b_out
// All matmuls bf16 MFMA (fp32 accum). Softmax in exp2 domain (Q rows of
// w_qkv pre-scaled by 0.125*log2e). Flash loop: double-buffered KV, ONE
// barrier per tile, S(kt+1) MFMA after the barrier overlaps softmax(kt+1);
// running max baked into MFMA C-init; row-sum l via ones-MFMA.
//
// ws: xt[4][4096][256]bf16 @0 | qb[16][4096][64] @8M | kb @16M |
//     vb[16][64][4096] @24M | att[4][4096][256] @32M | wqb @40M | wob after.

#define HW 4096
#define CIN 256
#define LOG2E_DIV8 0.18033688011112042f

typedef __attribute__((ext_vector_type(8))) short short8v;
typedef __attribute__((ext_vector_type(4))) short short4v;
typedef __attribute__((ext_vector_type(4))) float float4v;

static __device__ __forceinline__ unsigned short f2bf(float f) {
    unsigned int u = __float_as_uint(f);
    u += 0x7fff + ((u >> 16) & 1);   // RNE
    return (unsigned short)(u >> 16);
}
// packed f32x2 -> bf16x2 (lo <- a, hi <- b), RNE
static __device__ __forceinline__ unsigned int pkbf(float a, float b) {
    unsigned int r;
    asm("v_cvt_pk_bf16_f32 %0, %1, %2" : "=v"(r) : "v"(a), "v"(b));
    return r;
}

// ---------------------------------------------------------------------------
__global__ __launch_bounds__(256) void cast_w_k(
    const float* __restrict__ w_qkv, const float* __restrict__ w_out,
    unsigned short* __restrict__ wqb, unsigned short* __restrict__ wob)
{
    const int bi = blockIdx.x;
    if (bi < 192) {
        const int idx = bi * 1024 + threadIdx.x * 4;
        const float s = (idx < 256 * 256) ? LOG2E_DIV8 : 1.0f;  // Q rows
        const float4 v = *(const float4*)&w_qkv[idx];
        uint2 pk;
        pk.x = pkbf(v.x * s, v.y * s);
        pk.y = pkbf(v.z * s, v.w * s);
        *(uint2*)&wqb[idx] = pk;
    } else {
        const int idx = (bi - 192) * 1024 + threadIdx.x * 4;
        const float4 v = *(const float4*)&w_out[idx];
        uint2 pk;
        pk.x = pkbf(v.x, v.y);
        pk.y = pkbf(v.z, v.w);
        *(uint2*)&wob[idx] = pk;
    }
}

// ---------------------------------------------------------------------------
// cast + transpose x: [b][c][p] f32 -> xt [b][p][c] bf16
// ---------------------------------------------------------------------------
__global__ __launch_bounds__(256) void cast_x_k(
    const float* __restrict__ x, unsigned short* __restrict__ xt)
{
    const int p0 = blockIdx.x * 64, c0 = blockIdx.y * 64, b = blockIdx.z;
    const int t = threadIdx.x;
    __shared__ float tile[64][65];

    const float* xb = x + ((size_t)b * CIN + c0) * HW + p0;
    #pragma unroll
    for (int iter = 0; iter < 4; ++iter) {
        const int idx = iter * 1024 + t * 4;
        const int cc = idx >> 6, pp = idx & 63;
        const float4 v = *(const float4*)&xb[(size_t)cc * HW + pp];
        tile[cc][pp + 0] = v.x; tile[cc][pp + 1] = v.y;
        tile[cc][pp + 2] = v.z; tile[cc][pp + 3] = v.w;
    }
    __syncthreads();
    unsigned short* xo = xt + ((size_t)b * HW + p0) * CIN + c0;
    #pragma unroll
    for (int iter = 0; iter < 4; ++iter) {
        const int idx = iter * 1024 + t * 4;
        const int pp = idx >> 6, cc = idx & 63;
        uint2 pk;
        pk.x = pkbf(tile[cc + 0][pp], tile[cc + 1][pp]);
        pk.y = pkbf(tile[cc + 2][pp], tile[cc + 3][pp]);
        *(uint2*)&xo[(size_t)pp * CIN + cc] = pk;
    }
}

// ---------------------------------------------------------------------------
// qkv projection, bf16 MFMA, 128x128 tile, 4 waves, BK=64, swizzled LDS.
// ---------------------------------------------------------------------------
__global__ __launch_bounds__(256) void qkv_mfma_k(
    const unsigned short* __restrict__ wqb, const unsigned short* __restrict__ xt,
    unsigned short* __restrict__ qb, unsigned short* __restrict__ kb,
    unsigned short* __restrict__ vb)
{
    const int o0 = blockIdx.x * 128;
    const int p0 = blockIdx.y * 128;
    const int b  = blockIdx.z;
    const int t = threadIdx.x;
    const int wid = t >> 6, lane = t & 63, g = lane >> 4, li = lane & 15;
    const int wo = (wid >> 1) * 64, wp = (wid & 1) * 64;

    __shared__ char alds[16384];
    __shared__ char blds[16384];

    const int srow8 = t >> 3, sc16 = t & 7;
    const char* asrc = (const char*)wqb + ((size_t)(o0 + srow8) * 256) * 2 + sc16 * 16;
    const char* bsrc = (const char*)xt + (((size_t)b * HW + p0 + srow8) * 256) * 2 + sc16 * 16;

    float4 areg[4], breg[4];
    #pragma unroll
    for (int it = 0; it < 4; ++it) {
        areg[it] = *(const float4*)(asrc + (size_t)it * 32 * 512);
        breg[it] = *(const float4*)(bsrc + (size_t)it * 32 * 512);
    }

    float4v acc[4][4];
    #pragma unroll
    for (int mt = 0; mt < 4; ++mt)
        #pragma unroll
        for (int nt = 0; nt < 4; ++nt) acc[mt][nt] = (float4v){0.f, 0.f, 0.f, 0.f};

    for (int ks = 0; ks < 4; ++ks) {
        #pragma unroll
        for (int it = 0; it < 4; ++it) {
            const int row = it * 32 + srow8;
            const int dsw = row * 128 + ((sc16 * 16) ^ ((row & 7) << 4));
            *(float4*)(alds + dsw) = areg[it];
            *(float4*)(blds + dsw) = breg[it];
        }
        __syncthreads();
        if (ks < 3) {
            #pragma unroll
            for (int it = 0; it < 4; ++it) {
                areg[it] = *(const float4*)(asrc + (size_t)it * 32 * 512 + (ks + 1) * 128);
                breg[it] = *(const float4*)(bsrc + (size_t)it * 32 * 512 + (ks + 1) * 128);
            }
        }
        short8v af[4][2], bf[4][2];
        #pragma unroll
        for (int mt = 0; mt < 4; ++mt) {
            const int row = wo + mt * 16 + li;
            #pragma unroll
            for (int kc = 0; kc < 2; ++kc)
                af[mt][kc] = *(const short8v*)(alds + row * 128 + ((kc * 64 + g * 16) ^ ((row & 7) << 4)));
        }
        #pragma unroll
        for (int nt = 0; nt < 4; ++nt) {
            const int row = wp + nt * 16 + li;
            #pragma unroll
            for (int kc = 0; kc < 2; ++kc)
                bf[nt][kc] = *(const short8v*)(blds + row * 128 + ((kc * 64 + g * 16) ^ ((row & 7) << 4)));
        }
        #pragma unroll
        for (int mt = 0; mt < 4; ++mt)
            #pragma unroll
            for (int nt = 0; nt < 4; ++nt) {
                acc[mt][nt] = __builtin_amdgcn_mfma_f32_16x16x32_bf16(af[mt][0], bf[nt][0], acc[mt][nt], 0, 0, 0);
                acc[mt][nt] = __builtin_amdgcn_mfma_f32_16x16x32_bf16(af[mt][1], bf[nt][1], acc[mt][nt], 0, 0, 0);
            }
        __syncthreads();
    }

    const int which = o0 >> 8;            // 0=Q 1=K 2=V
    #pragma unroll
    for (int mt = 0; mt < 4; ++mt) {
        const int o_b = o0 + wo + mt * 16 + g * 4;
        const int head = (o_b >> 6) & 3;
        const int dd = o_b & 63;
        const int bh = b * 4 + head;
        if (which < 2) {
            unsigned short* dst = which ? kb : qb;
            #pragma unroll
            for (int nt = 0; nt < 4; ++nt) {
                const int p = p0 + wp + nt * 16 + li;
                uint2 pk;
                pk.x = pkbf(acc[mt][nt][0], acc[mt][nt][1]);
                pk.y = pkbf(acc[mt][nt][2], acc[mt][nt][3]);
                *(uint2*)&dst[((size_t)bh * HW + p) * 64 + dd] = pk;
            }
        } else {
            #pragma unroll
            for (int nt = 0; nt < 4; ++nt) {
                const int p = p0 + wp + nt * 16 + li;
                #pragma unroll
                for (int r = 0; r < 4; ++r)
                    vb[((size_t)bh * 64 + dd + r) * HW + p] = f2bf(acc[mt][nt][r]);
            }
        }
    }
}

// ---------------------------------------------------------------------------
// flash attention: 256 threads = 4 waves x 32 q-rows (2 q-tiles); KV-tile 64.
// Pipelined single-barrier loop, double-buffered K/V, running-max baked into
// S-MFMA C-init, l via ones-MFMA, setprio around MFMA clusters.
// ---------------------------------------------------------------------------
__global__ __launch_bounds__(256) void flash_mfma_k(
    const unsigned short* __restrict__ qb, const unsigned short* __restrict__ kb,
    const unsigned short* __restrict__ vb, unsigned short* __restrict__ att)
{
    const int i0 = blockIdx.x * 128;      // 32
    const int bh = blockIdx.y;            // 16
    const int t = threadIdx.x;
    const int wid = t >> 6, lane = t & 63, g = lane >> 4, li = lane & 15;
    const int b = bh >> 2, head = bh & 3;

    const unsigned short* qg = qb + (size_t)bh * HW * 64;
    const unsigned short* kg = kb + (size_t)bh * HW * 64;
    const unsigned short* vg = vb + (size_t)bh * 64 * HW;

    __shared__ char klds[2][8192];        // [buf][64 j][64 d] swizzled
    __shared__ char vlds[2][8192];        // [buf][64 d][64 j] swizzled
    __shared__ short plds[4][32][72];     // per-wave P [q][j]

    short8v qf[2][2];
    #pragma unroll
    for (int qt = 0; qt < 2; ++qt)
        #pragma unroll
        for (int c = 0; c < 2; ++c) {
            const int q = i0 + wid * 32 + qt * 16 + li;
            qf[qt][c] = *(const short8v*)(qg + (size_t)q * 64 + c * 32 + g * 8);
        }

    short8v ones;
    #pragma unroll
    for (int i = 0; i < 8; ++i) ones[i] = (short)0x3F80;   // bf16 1.0

    float m[2] = {0.f, 0.f};              // running max (exp2 domain)
    float4v acco[4][2];                   // O^T accs [dt][qt]
    float4v accl[2];                      // l accs (ones-MFMA), reg0 = full sum
    float4v accs[4][2];                   // S^T of current tile [jt][qt]
    #pragma unroll
    for (int dt = 0; dt < 4; ++dt)
        #pragma unroll
        for (int qt = 0; qt < 2; ++qt) acco[dt][qt] = (float4v){0.f, 0.f, 0.f, 0.f};
    accl[0] = (float4v){0.f, 0.f, 0.f, 0.f};
    accl[1] = (float4v){0.f, 0.f, 0.f, 0.f};

    // staging: 2 chunks/thread/buffer
    const int srow0 = t >> 3, sc0 = t & 7;
    const int srow1 = (t + 256) >> 3;
    const int dsw0 = srow0 * 128 + ((sc0 * 16) ^ ((srow0 & 7) << 4));
    const int dsw1 = srow1 * 128 + ((sc0 * 16) ^ ((srow1 & 7) << 4));
    const char* ksrc0 = (const char*)kg + (size_t)srow0 * 128 + sc0 * 16;
    const char* ksrc1 = (const char*)kg + (size_t)srow1 * 128 + sc0 * 16;
    const char* vsrc0 = (const char*)vg + (size_t)srow0 * 8192 + sc0 * 16;
    const char* vsrc1 = (const char*)vg + (size_t)srow1 * 8192 + sc0 * 16;

    float4 kregA, kregB, vregA, vregB;

    auto LOADT = [&](int tile) {
        kregA = *(const float4*)(ksrc0 + (size_t)tile * 8192);
        kregB = *(const float4*)(ksrc1 + (size_t)tile * 8192);
        vregA = *(const float4*)(vsrc0 + (size_t)tile * 128);
        vregB = *(const float4*)(vsrc1 + (size_t)tile * 128);
    };
    auto WRITET = [&](int buf) {
        *(float4*)(klds[buf] + dsw0) = kregA;
        *(float4*)(klds[buf] + dsw1) = kregB;
        *(float4*)(vlds[buf] + dsw0) = vregA;
        *(float4*)(vlds[buf] + dsw1) = vregB;
    };
    // S^T = K·Q^T with C-init = -m  (so accs = s - m directly)
    auto SMM = [&](int buf) {
        #pragma unroll
        for (int jt = 0; jt < 4; ++jt) {
            accs[jt][0] = (float4v){-m[0], -m[0], -m[0], -m[0]};
            accs[jt][1] = (float4v){-m[1], -m[1], -m[1], -m[1]};
        }
        __builtin_amdgcn_s_setprio(1);
        #pragma unroll
        for (int jt = 0; jt < 4; ++jt) {
            const int row = jt * 16 + li;
            #pragma unroll
            for (int c = 0; c < 2; ++c) {
                const short8v kf = *(const short8v*)(klds[buf] + row * 128 + ((c * 64 + g * 16) ^ ((row & 7) << 4)));
                accs[jt][0] = __builtin_amdgcn_mfma_f32_16x16x32_bf16(kf, qf[0][c], accs[jt][0], 0, 0, 0);
                accs[jt][1] = __builtin_amdgcn_mfma_f32_16x16x32_bf16(kf, qf[1][c], accs[jt][1], 0, 0, 0);
            }
        }
        __builtin_amdgcn_s_setprio(0);
    };
    // softmax on accs (already s - m): threshold check, exp2, pack to plds
    auto SOFT = [&]() {
        float tadj[2];
        #pragma unroll
        for (int qt = 0; qt < 2; ++qt) {
            float t0 = fmaxf(fmaxf(accs[0][qt][0], accs[0][qt][1]), fmaxf(accs[0][qt][2], accs[0][qt][3]));
            float t1 = fmaxf(fmaxf(accs[1][qt][0], accs[1][qt][1]), fmaxf(accs[1][qt][2], accs[1][qt][3]));
            float t2 = fmaxf(fmaxf(accs[2][qt][0], accs[2][qt][1]), fmaxf(accs[2][qt][2], accs[2][qt][3]));
            float t3 = fmaxf(fmaxf(accs[3][qt][0], accs[3][qt][1]), fmaxf(accs[3][qt][2], accs[3][qt][3]));
            float tm = fmaxf(fmaxf(t0, t1), fmaxf(t2, t3));
            tm = fmaxf(tm, __shfl_xor(tm, 16, 64));
            tm = fmaxf(tm, __shfl_xor(tm, 32, 64));
            tadj[qt] = tm;
        }
        if (__any(fmaxf(tadj[0], tadj[1]) > 8.0f)) {       // rare
            #pragma unroll
            for (int qt = 0; qt < 2; ++qt) {
                const float delta = fmaxf(tadj[qt], 0.f);
                const float fsc = __builtin_amdgcn_exp2f(-delta);
                m[qt] += delta;
                #pragma unroll
                for (int dt = 0; dt < 4; ++dt) {
                    acco[dt][qt][0] *= fsc; acco[dt][qt][1] *= fsc;
                    acco[dt][qt][2] *= fsc; acco[dt][qt][3] *= fsc;
                }
                accl[qt][0] *= fsc; accl[qt][1] *= fsc;
                accl[qt][2] *= fsc; accl[qt][3] *= fsc;
                #pragma unroll
                for (int jt = 0; jt < 4; ++jt) {
                    accs[jt][qt][0] -= delta; accs[jt][qt][1] -= delta;
                    accs[jt][qt][2] -= delta; accs[jt][qt][3] -= delta;
                }
            }
        }
        #pragma unroll
        for (int qt = 0; qt < 2; ++qt) {
            #pragma unroll
            for (int jt = 0; jt < 4; ++jt) {
                const float p0 = __builtin_amdgcn_exp2f(accs[jt][qt][0]);
                const float p1 = __builtin_amdgcn_exp2f(accs[jt][qt][1]);
                const float p2 = __builtin_amdgcn_exp2f(accs[jt][qt][2]);
                const float p3 = __builtin_amdgcn_exp2f(accs[jt][qt][3]);
                uint2 pk;
                pk.x = pkbf(p0, p1);
                pk.y = pkbf(p2, p3);
                *(uint2*)&plds[wid][qt * 16 + li][jt * 16 + 4 * g] = pk;
            }
        }
    };
    // PV (+ l ones-MFMA): O^T += V^T·P^T
    auto PVMM = [&](int buf) {
        short8v pf[2][2];
        #pragma unroll
        for (int qt = 0; qt < 2; ++qt)
            #pragma unroll
            for (int c = 0; c < 2; ++c)
                pf[qt][c] = *(const short8v*)((const char*)&plds[wid][qt * 16 + li][0] + c * 64 + g * 16);
        __builtin_amdgcn_s_setprio(1);
        #pragma unroll
        for (int qt = 0; qt < 2; ++qt) {
            accl[qt] = __builtin_amdgcn_mfma_f32_16x16x32_bf16(ones, pf[qt][0], accl[qt], 0, 0, 0);
            accl[qt] = __builtin_amdgcn_mfma_f32_16x16x32_bf16(ones, pf[qt][1], accl[qt], 0, 0, 0);
        }
        #pragma unroll
        for (int dt = 0; dt < 4; ++dt) {
            const int row = dt * 16 + li;
            #pragma unroll
            for (int c = 0; c < 2; ++c) {
                const short8v vf = *(const short8v*)(vlds[buf] + row * 128 + ((c * 64 + g * 16) ^ ((row & 7) << 4)));
                acco[dt][0] = __builtin_amdgcn_mfma_f32_16x16x32_bf16(vf, pf[0][c], acco[dt][0], 0, 0, 0);
                acco[dt][1] = __builtin_amdgcn_mfma_f32_16x16x32_bf16(vf, pf[1][c], acco[dt][1], 0, 0, 0);
            }
        }
        __builtin_amdgcn_s_setprio(0);
    };

    // prologue: stage tile 0, prefetch tile 1, S(0)
    LOADT(0);
    WRITET(0);
    LOADT(1);
    __syncthreads();
    SMM(0);

    for (int kt = 0; kt < 63; ++kt) {
        const int nb = (kt + 1) & 1;
        WRITET(nb);                        // regs hold tile kt+1
        const int pref = (kt + 2 < 64) ? kt + 2 : 63;
        LOADT(pref);                       // prefetch tile kt+2 (clamped)
        SOFT();                            // softmax(kt) -> plds (per-wave)
        PVMM(kt & 1);                      // PV(kt)
        __syncthreads();                   // buf[nb] ready; buf[kt&1] free next iter
        SMM(nb);                           // S(kt+1), overlaps next soft
    }
    SOFT();
    PVMM(1);                               // tile 63 in buf 1

    // epilogue: l from accl (all regs equal), write O bf16 att[b][p][c]
    #pragma unroll
    for (int qt = 0; qt < 2; ++qt) {
        const float inv = 1.0f / accl[qt][0];
        const int q = i0 + wid * 32 + qt * 16 + li;
        #pragma unroll
        for (int dt = 0; dt < 4; ++dt) {
            uint2 pk;
            pk.x = pkbf(acco[dt][qt][0] * inv, acco[dt][qt][1] * inv);
            pk.y = pkbf(acco[dt][qt][2] * inv, acco[dt][qt][3] * inv);
            *(uint2*)&att[((size_t)b * HW + q) * CIN + head * 64 + dt * 16 + 4 * g] = pk;
        }
    }
}

// ---------------------------------------------------------------------------
// output projection, bf16 MFMA + bias + residual (fp32 out).
// ---------------------------------------------------------------------------
__global__ __launch_bounds__(256) void proj_mfma_k(
    const unsigned short* __restrict__ wob, const unsigned short* __restrict__ att,
    const float* __restrict__ bias, const float* __restrict__ x,
    float* __restrict__ out)
{
    const int o0 = blockIdx.x * 128;
    const int p0 = blockIdx.y * 128;
    const int b  = blockIdx.z;
    const int t = threadIdx.x;
    const int wid = t >> 6, lane = t & 63, g = lane >> 4, li = lane & 15;
    const int wo = (wid >> 1) * 64, wp = (wid & 1) * 64;

    __shared__ char alds[16384];
    __shared__ char blds[16384];

    const int srow8 = t >> 3, sc16 = t & 7;
    const char* asrc = (const char*)wob + ((size_t)(o0 + srow8) * 256) * 2 + sc16 * 16;
    const char* bsrc = (const char*)att + (((size_t)b * HW + p0 + srow8) * 256) * 2 + sc16 * 16;

    float4 areg[4], breg[4];
    #pragma unroll
    for (int it = 0; it < 4; ++it) {
        areg[it] = *(const float4*)(asrc + (size_t)it * 32 * 512);
        breg[it] = *(const float4*)(bsrc + (size_t)it * 32 * 512);
    }

    float4v acc[4][4];
    #pragma unroll
    for (int mt = 0; mt < 4; ++mt)
        #pragma unroll
        for (int nt = 0; nt < 4; ++nt) acc[mt][nt] = (float4v){0.f, 0.f, 0.f, 0.f};

    for (int ks = 0; ks < 4; ++ks) {
        #pragma unroll
        for (int it = 0; it < 4; ++it) {
            const int row = it * 32 + srow8;
            const int dsw = row * 128 + ((sc16 * 16) ^ ((row & 7) << 4));
            *(float4*)(alds + dsw) = areg[it];
            *(float4*)(blds + dsw) = breg[it];
        }
        __syncthreads();
        if (ks < 3) {
            #pragma unroll
            for (int it = 0; it < 4; ++it) {
                areg[it] = *(const float4*)(asrc + (size_t)it * 32 * 512 + (ks + 1) * 128);
                breg[it] = *(const float4*)(bsrc + (size_t)it * 32 * 512 + (ks + 1) * 128);
            }
        }
        short8v af[4][2], bf[4][2];
        #pragma unroll
        for (int mt = 0; mt < 4; ++mt) {
            const int row = wo + mt * 16 + li;
            #pragma unroll
            for (int kc = 0; kc < 2; ++kc)
                af[mt][kc] = *(const short8v*)(alds + row * 128 + ((kc * 64 + g * 16) ^ ((row & 7) << 4)));
        }
        #pragma unroll
        for (int nt = 0; nt < 4; ++nt) {
            const int row = wp + nt * 16 + li;
            #pragma unroll
            for (int kc = 0; kc < 2; ++kc)
                bf[nt][kc] = *(const short8v*)(blds + row * 128 + ((kc * 64 + g * 16) ^ ((row & 7) << 4)));
        }
        #pragma unroll
        for (int mt = 0; mt < 4; ++mt)
            #pragma unroll
            for (int nt = 0; nt < 4; ++nt) {
                acc[mt][nt] = __builtin_amdgcn_mfma_f32_16x16x32_bf16(af[mt][0], bf[nt][0], acc[mt][nt], 0, 0, 0);
                acc[mt][nt] = __builtin_amdgcn_mfma_f32_16x16x32_bf16(af[mt][1], bf[nt][1], acc[mt][nt], 0, 0, 0);
            }
        __syncthreads();
    }

    #pragma unroll
    for (int mt = 0; mt < 4; ++mt) {
        const int o_b = o0 + wo + mt * 16 + g * 4;
        #pragma unroll
        for (int nt = 0; nt < 4; ++nt) {
            const int p = p0 + wp + nt * 16 + li;
            #pragma unroll
            for (int r = 0; r < 4; ++r) {
                const int o = o_b + r;
                const size_t ix = ((size_t)b * CIN + o) * HW + p;
                out[ix] = acc[mt][nt][r] + bias[o] + x[ix];
            }
        }
    }
}

extern "C" void kernel_launch(void* const* d_in, const int* in_sizes, int n_in,
                              void* d_out, int out_size, void* d_ws, size_t ws_size,
                              hipStream_t stream)
{
    const float* x     = (const float*)d_in[0];
    const float* w_qkv = (const float*)d_in[1];
    const float* w_out = (const float*)d_in[2];
    const float* b_out = (const float*)d_in[3];
    float* out = (float*)d_out;

    char* ws = (char*)d_ws;
    const size_t MB = 1024 * 1024;
    unsigned short* xt  = (unsigned short*)(ws);
    unsigned short* qb  = (unsigned short*)(ws + 8 * MB);
    unsigned short* kb  = (unsigned short*)(ws + 16 * MB);
    unsigned short* vb  = (unsigned short*)(ws + 24 * MB);
    unsigned short* att = (unsigned short*)(ws + 32 * MB);
    unsigned short* wqb = (unsigned short*)(ws + 40 * MB);
    unsigned short* wob = (unsigned short*)(ws + 40 * MB + 768 * 256 * 2);

    cast_w_k<<<256, 256, 0, stream>>>(w_qkv, w_out, wqb, wob);
    cast_x_k<<<dim3(64, 4, 4), 256, 0, stream>>>(x, xt);
    qkv_mfma_k<<<dim3(6, 32, 4), 256, 0, stream>>>(wqb, xt, qb, kb, vb);
    flash_mfma_k<<<dim3(32, 16), 256, 0, stream>>>(qb, kb, vb, att);
    proj_mfma_k<<<dim3(2, 32, 4), 256, 0, stream>>>(wob, att, b_out, x, out);
}

// Round 6
// 162.652 us; speedup vs baseline: 16.8518x; 1.0111x over previous
//
#include <hip/hip_runtime.h>

// AttentionBlock: x(4,256,64,64) fp32
//   qkv = w_qkv(768,256) @ x ; flash attention (heads=4, d=64, N=4096, 16 bh);
//   out = x + w_out @ att + b_out
// All matmuls bf16 MFMA (fp32 accum). Flash uses 32x32x16 MFMA with fully
// in-register softmax: S^T = K.Q^T puts one q-column per lane; P -> bf16 via
// v_cvt_pk_bf16_f32 + v_permlane32_swap_b32 (no LDS for P). Softmax in exp2
// domain (Q rows of w_qkv pre-scaled by 0.125*log2e). Single-barrier
// double-buffered KV pipeline; row-sum l via ones-MFMA; defer-max thr 8.
//
// ws: xt[4][4096][256]bf16 @0 | qb[16][4096][64] @8M | kb @16M |
//     vb[16][64][4096] @24M | att[4][4096][256] @32M | wqb @40M | wob after.

#define HW 4096
#define CIN 256
#define LOG2E_DIV8 0.18033688011112042f

typedef __attribute__((ext_vector_type(8))) short short8v;
typedef __attribute__((ext_vector_type(4))) short short4v;
typedef __attribute__((ext_vector_type(4))) float float4v;
typedef __attribute__((ext_vector_type(16))) float f32x16;
typedef __attribute__((ext_vector_type(4))) unsigned int uint4v;

static __device__ __forceinline__ unsigned short f2bf(float f) {
    unsigned int u = __float_as_uint(f);
    u += 0x7fff + ((u >> 16) & 1);   // RNE
    return (unsigned short)(u >> 16);
}
// packed f32x2 -> bf16x2 (lo <- a, hi <- b), RNE
static __device__ __forceinline__ unsigned int pkbf(float a, float b) {
    unsigned int r;
    asm("v_cvt_pk_bf16_f32 %0, %1, %2" : "=v"(r) : "v"(a), "v"(b));
    return r;
}
// v_permlane32_swap_b32: a[32:63] <-> b[0:31]
static __device__ __forceinline__ void pl32swap(unsigned int& a, unsigned int& b) {
    asm volatile("v_permlane32_swap_b32 %0, %1" : "+v"(a), "+v"(b));
}

// ---------------------------------------------------------------------------
__global__ __launch_bounds__(256) void cast_w_k(
    const float* __restrict__ w_qkv, const float* __restrict__ w_out,
    unsigned short* __restrict__ wqb, unsigned short* __restrict__ wob)
{
    const int bi = blockIdx.x;
    if (bi < 192) {
        const int idx = bi * 1024 + threadIdx.x * 4;
        const float s = (idx < 256 * 256) ? LOG2E_DIV8 : 1.0f;  // Q rows
        const float4 v = *(const float4*)&w_qkv[idx];
        uint2 pk;
        pk.x = pkbf(v.x * s, v.y * s);
        pk.y = pkbf(v.z * s, v.w * s);
        *(uint2*)&wqb[idx] = pk;
    } else {
        const int idx = (bi - 192) * 1024 + threadIdx.x * 4;
        const float4 v = *(const float4*)&w_out[idx];
        uint2 pk;
        pk.x = pkbf(v.x, v.y);
        pk.y = pkbf(v.z, v.w);
        *(uint2*)&wob[idx] = pk;
    }
}

// ---------------------------------------------------------------------------
// cast + transpose x: [b][c][p] f32 -> xt [b][p][c] bf16
// ---------------------------------------------------------------------------
__global__ __launch_bounds__(256) void cast_x_k(
    const float* __restrict__ x, unsigned short* __restrict__ xt)
{
    const int p0 = blockIdx.x * 64, c0 = blockIdx.y * 64, b = blockIdx.z;
    const int t = threadIdx.x;
    __shared__ float tile[64][65];

    const float* xb = x + ((size_t)b * CIN + c0) * HW + p0;
    #pragma unroll
    for (int iter = 0; iter < 4; ++iter) {
        const int idx = iter * 1024 + t * 4;
        const int cc = idx >> 6, pp = idx & 63;
        const float4 v = *(const float4*)&xb[(size_t)cc * HW + pp];
        tile[cc][pp + 0] = v.x; tile[cc][pp + 1] = v.y;
        tile[cc][pp + 2] = v.z; tile[cc][pp + 3] = v.w;
    }
    __syncthreads();
    unsigned short* xo = xt + ((size_t)b * HW + p0) * CIN + c0;
    #pragma unroll
    for (int iter = 0; iter < 4; ++iter) {
        const int idx = iter * 1024 + t * 4;
        const int pp = idx >> 6, cc = idx & 63;
        uint2 pk;
        pk.x = pkbf(tile[cc + 0][pp], tile[cc + 1][pp]);
        pk.y = pkbf(tile[cc + 2][pp], tile[cc + 3][pp]);
        *(uint2*)&xo[(size_t)pp * CIN + cc] = pk;
    }
}

// ---------------------------------------------------------------------------
// qkv projection, bf16 MFMA, 128x128 tile, 4 waves, BK=64, swizzled LDS.
// ---------------------------------------------------------------------------
__global__ __launch_bounds__(256) void qkv_mfma_k(
    const unsigned short* __restrict__ wqb, const unsigned short* __restrict__ xt,
    unsigned short* __restrict__ qb, unsigned short* __restrict__ kb,
    unsigned short* __restrict__ vb)
{
    const int o0 = blockIdx.x * 128;
    const int p0 = blockIdx.y * 128;
    const int b  = blockIdx.z;
    const int t = threadIdx.x;
    const int wid = t >> 6, lane = t & 63, g = lane >> 4, li = lane & 15;
    const int wo = (wid >> 1) * 64, wp = (wid & 1) * 64;

    __shared__ char alds[16384];
    __shared__ char blds[16384];

    const int srow8 = t >> 3, sc16 = t & 7;
    const char* asrc = (const char*)wqb + ((size_t)(o0 + srow8) * 256) * 2 + sc16 * 16;
    const char* bsrc = (const char*)xt + (((size_t)b * HW + p0 + srow8) * 256) * 2 + sc16 * 16;

    float4 areg[4], breg[4];
    #pragma unroll
    for (int it = 0; it < 4; ++it) {
        areg[it] = *(const float4*)(asrc + (size_t)it * 32 * 512);
        breg[it] = *(const float4*)(bsrc + (size_t)it * 32 * 512);
    }

    float4v acc[4][4];
    #pragma unroll
    for (int mt = 0; mt < 4; ++mt)
        #pragma unroll
        for (int nt = 0; nt < 4; ++nt) acc[mt][nt] = (float4v){0.f, 0.f, 0.f, 0.f};

    for (int ks = 0; ks < 4; ++ks) {
        #pragma unroll
        for (int it = 0; it < 4; ++it) {
            const int row = it * 32 + srow8;
            const int dsw = row * 128 + ((sc16 * 16) ^ ((row & 7) << 4));
            *(float4*)(alds + dsw) = areg[it];
            *(float4*)(blds + dsw) = breg[it];
        }
        __syncthreads();
        if (ks < 3) {
            #pragma unroll
            for (int it = 0; it < 4; ++it) {
                areg[it] = *(const float4*)(asrc + (size_t)it * 32 * 512 + (ks + 1) * 128);
                breg[it] = *(const float4*)(bsrc + (size_t)it * 32 * 512 + (ks + 1) * 128);
            }
        }
        short8v af[4][2], bf[4][2];
        #pragma unroll
        for (int mt = 0; mt < 4; ++mt) {
            const int row = wo + mt * 16 + li;
            #pragma unroll
            for (int kc = 0; kc < 2; ++kc)
                af[mt][kc] = *(const short8v*)(alds + row * 128 + ((kc * 64 + g * 16) ^ ((row & 7) << 4)));
        }
        #pragma unroll
        for (int nt = 0; nt < 4; ++nt) {
            const int row = wp + nt * 16 + li;
            #pragma unroll
            for (int kc = 0; kc < 2; ++kc)
                bf[nt][kc] = *(const short8v*)(blds + row * 128 + ((kc * 64 + g * 16) ^ ((row & 7) << 4)));
        }
        #pragma unroll
        for (int mt = 0; mt < 4; ++mt)
            #pragma unroll
            for (int nt = 0; nt < 4; ++nt) {
                acc[mt][nt] = __builtin_amdgcn_mfma_f32_16x16x32_bf16(af[mt][0], bf[nt][0], acc[mt][nt], 0, 0, 0);
                acc[mt][nt] = __builtin_amdgcn_mfma_f32_16x16x32_bf16(af[mt][1], bf[nt][1], acc[mt][nt], 0, 0, 0);
            }
        __syncthreads();
    }

    const int which = o0 >> 8;            // 0=Q 1=K 2=V
    #pragma unroll
    for (int mt = 0; mt < 4; ++mt) {
        const int o_b = o0 + wo + mt * 16 + g * 4;
        const int head = (o_b >> 6) & 3;
        const int dd = o_b & 63;
        const int bh = b * 4 + head;
        if (which < 2) {
            unsigned short* dst = which ? kb : qb;
            #pragma unroll
            for (int nt = 0; nt < 4; ++nt) {
                const int p = p0 + wp + nt * 16 + li;
                uint2 pk;
                pk.x = pkbf(acc[mt][nt][0], acc[mt][nt][1]);
                pk.y = pkbf(acc[mt][nt][2], acc[mt][nt][3]);
                *(uint2*)&dst[((size_t)bh * HW + p) * 64 + dd] = pk;
            }
        } else {
            #pragma unroll
            for (int nt = 0; nt < 4; ++nt) {
                const int p = p0 + wp + nt * 16 + li;
                #pragma unroll
                for (int r = 0; r < 4; ++r)
                    vb[((size_t)bh * 64 + dd + r) * HW + p] = f2bf(acc[mt][nt][r]);
            }
        }
    }
}

// ---------------------------------------------------------------------------
// flash attention: 256 threads = 4 waves x 32 q-rows; KV-tile 64, 32x32 MFMA.
// Lane owns q = lane&31 (both half-waves). In-register softmax & P (T12).
// Single-barrier pipelined loop, double-buffered KV, defer-max, l ones-MFMA.
// ---------------------------------------------------------------------------
__global__ __launch_bounds__(256) void flash_mfma_k(
    const unsigned short* __restrict__ qb, const unsigned short* __restrict__ kb,
    const unsigned short* __restrict__ vb, unsigned short* __restrict__ att)
{
    const int i0 = blockIdx.x * 128;      // 32
    const int bh = blockIdx.y;            // 16
    const int t = threadIdx.x;
    const int wid = t >> 6, lane = t & 63;
    const int q32 = lane & 31, hi = lane >> 5;
    const int b = bh >> 2, head = bh & 3;

    const unsigned short* qg = qb + (size_t)bh * HW * 64;
    const unsigned short* kg = kb + (size_t)bh * HW * 64;
    const unsigned short* vg = vb + (size_t)bh * 64 * HW;

    __shared__ char klds[2][8192];        // [buf][64 j][64 d] bf16, swizzled
    __shared__ char vlds[2][8192];        // [buf][64 d][64 j] bf16, swizzled

    // Q B-frags: qf[kc][i] = Q[q][kc*16 + hi*8 + i]
    const int q = i0 + wid * 32 + q32;
    short8v qf[4];
    #pragma unroll
    for (int kc = 0; kc < 4; ++kc)
        qf[kc] = *(const short8v*)(qg + (size_t)q * 64 + kc * 16 + hi * 8);

    short8v ones;
    #pragma unroll
    for (int i = 0; i < 8; ++i) ones[i] = (short)0x3F80;   // bf16 1.0

    float m = 0.f;                         // running max (exp2 domain), per-lane q
    f32x16 acco[2];                        // O^T accs [dt]: d = dt*32+(r&3)+8*(r>>2)+4*hi
    f32x16 accl;                           // l acc (ones-MFMA); only reg0 consumed
    f32x16 accs[2];                        // S^T [jt]: j = jt*32+(r&3)+8*(r>>2)+4*hi
    short8v pf[2][2];                      // P^T B-frags [jt][kc_rel]
    #pragma unroll
    for (int r = 0; r < 16; ++r) { acco[0][r] = 0.f; acco[1][r] = 0.f; accl[r] = 0.f; }

    // staging: 2 chunks/thread/buffer (8 KB per buffer, 256 threads)
    const int srow0 = t >> 3, sc0 = t & 7;
    const int srow1 = srow0 + 32;
    const int dsw0 = srow0 * 128 + ((sc0 * 16) ^ ((srow0 & 7) << 4));
    const int dsw1 = srow1 * 128 + ((sc0 * 16) ^ ((srow1 & 7) << 4));
    const char* ksrc0 = (const char*)kg + (size_t)srow0 * 128 + sc0 * 16;
    const char* ksrc1 = (const char*)kg + (size_t)srow1 * 128 + sc0 * 16;
    const char* vsrc0 = (const char*)vg + (size_t)srow0 * 8192 + sc0 * 16;
    const char* vsrc1 = (const char*)vg + (size_t)srow1 * 8192 + sc0 * 16;

    float4 kregA, kregB, vregA, vregB;

    auto LOADT = [&](int tile) {
        kregA = *(const float4*)(ksrc0 + (size_t)tile * 8192);
        kregB = *(const float4*)(ksrc1 + (size_t)tile * 8192);
        vregA = *(const float4*)(vsrc0 + (size_t)tile * 128);
        vregB = *(const float4*)(vsrc1 + (size_t)tile * 128);
    };
    auto WRITET = [&](int buf) {
        *(float4*)(klds[buf] + dsw0) = kregA;
        *(float4*)(klds[buf] + dsw1) = kregB;
        *(float4*)(vlds[buf] + dsw0) = vregA;
        *(float4*)(vlds[buf] + dsw1) = vregB;
    };
    // S^T = K·Q^T, C-init = -m (accs = s - m directly)
    auto SMM = [&](int buf) {
        #pragma unroll
        for (int r = 0; r < 16; ++r) { accs[0][r] = -m; accs[1][r] = -m; }
        __builtin_amdgcn_s_setprio(1);
        #pragma unroll
        for (int jt = 0; jt < 2; ++jt) {
            const int row = jt * 32 + q32;
            const char* kbase = klds[buf] + row * 128;
            const int sw = (row & 7) << 4;
            #pragma unroll
            for (int kc = 0; kc < 4; ++kc) {
                const short8v kf = *(const short8v*)(kbase + ((kc * 32 + hi * 16) ^ sw));
                accs[jt] = __builtin_amdgcn_mfma_f32_32x32x16_bf16(kf, qf[kc], accs[jt], 0, 0, 0);
            }
        }
        __builtin_amdgcn_s_setprio(0);
    };
    // softmax on accs (= s - m): defer-max, exp2, pack+permlane into pf
    auto SOFT = [&]() {
        float mx[16];
        #pragma unroll
        for (int r = 0; r < 16; ++r) mx[r] = fmaxf(accs[0][r], accs[1][r]);
        #pragma unroll
        for (int s = 8; s > 0; s >>= 1)
            #pragma unroll
            for (int r = 0; r < s; ++r) mx[r] = fmaxf(mx[r], mx[r + s]);
        const float tm = fmaxf(mx[0], __shfl_xor(mx[0], 32, 64));
        if (__any(tm > 8.0f)) {            // rare
            const float delta = fmaxf(tm, 0.f);
            const float fsc = __builtin_amdgcn_exp2f(-delta);
            m += delta;
            accl[0] *= fsc;
            #pragma unroll
            for (int r = 0; r < 16; ++r) { acco[0][r] *= fsc; acco[1][r] *= fsc; }
            #pragma unroll
            for (int r = 0; r < 16; ++r) { accs[0][r] -= delta; accs[1][r] -= delta; }
        }
        #pragma unroll
        for (int jt = 0; jt < 2; ++jt) {
            float p[16];
            #pragma unroll
            for (int r = 0; r < 16; ++r) p[r] = __builtin_amdgcn_exp2f(accs[jt][r]);
            unsigned int w0 = pkbf(p[0], p[1]);
            unsigned int w1 = pkbf(p[2], p[3]);
            unsigned int w2 = pkbf(p[4], p[5]);
            unsigned int w3 = pkbf(p[6], p[7]);
            pl32swap(w0, w2);
            pl32swap(w1, w3);
            uint4v fa; fa[0] = w0; fa[1] = w1; fa[2] = w2; fa[3] = w3;
            pf[jt][0] = __builtin_bit_cast(short8v, fa);
            unsigned int w4 = pkbf(p[8],  p[9]);
            unsigned int w5 = pkbf(p[10], p[11]);
            unsigned int w6 = pkbf(p[12], p[13]);
            unsigned int w7 = pkbf(p[14], p[15]);
            pl32swap(w4, w6);
            pl32swap(w5, w7);
            uint4v fb; fb[0] = w4; fb[1] = w5; fb[2] = w6; fb[3] = w7;
            pf[jt][1] = __builtin_bit_cast(short8v, fb);
        }
    };
    // PV: O^T += V^T·P^T ; l += ones·P^T
    auto PVMM = [&](int buf) {
        __builtin_amdgcn_s_setprio(1);
        #pragma unroll
        for (int jt = 0; jt < 2; ++jt)
            #pragma unroll
            for (int kr = 0; kr < 2; ++kr)
                accl = __builtin_amdgcn_mfma_f32_32x32x16_bf16(ones, pf[jt][kr], accl, 0, 0, 0);
        #pragma unroll
        for (int dt = 0; dt < 2; ++dt) {
            const int row = dt * 32 + q32;
            const char* vbase = vlds[buf] + row * 128;
            const int sw = (row & 7) << 4;
            #pragma unroll
            for (int jt = 0; jt < 2; ++jt)
                #pragma unroll
                for (int kr = 0; kr < 2; ++kr) {
                    const short8v vf = *(const short8v*)(vbase + ((jt * 64 + kr * 32 + hi * 16) ^ sw));
                    acco[dt] = __builtin_amdgcn_mfma_f32_32x32x16_bf16(vf, pf[jt][kr], acco[dt], 0, 0, 0);
                }
        }
        __builtin_amdgcn_s_setprio(0);
    };

    // prologue: stage tile 0, prefetch tile 1, S(0)
    LOADT(0);
    WRITET(0);
    LOADT(1);
    __syncthreads();
    SMM(0);

    for (int kt = 0; kt < 63; ++kt) {
        const int nb = (kt + 1) & 1;
        WRITET(nb);                        // regs hold tile kt+1
        const int pref = (kt + 2 < 64) ? kt + 2 : 63;
        LOADT(pref);                       // prefetch tile kt+2 (clamped)
        SOFT();                            // softmax(kt), in-register
        PVMM(kt & 1);                      // PV(kt)
        __syncthreads();                   // buf[nb] ready; buf[kt&1] free next iter
        SMM(nb);                           // S(kt+1)
    }
    SOFT();
    PVMM(1);                               // tile 63 in buf 1

    // epilogue: O^T/l -> att bf16 [b][p=q][c = head*64 + d]
    const float inv = 1.0f / accl[0];
    unsigned short* ao = att + ((size_t)b * HW + q) * CIN + head * 64;
    #pragma unroll
    for (int dt = 0; dt < 2; ++dt)
        #pragma unroll
        for (int g4 = 0; g4 < 4; ++g4) {
            const int d = dt * 32 + 8 * g4 + 4 * hi;
            uint2 pk;
            pk.x = pkbf(acco[dt][g4 * 4 + 0] * inv, acco[dt][g4 * 4 + 1] * inv);
            pk.y = pkbf(acco[dt][g4 * 4 + 2] * inv, acco[dt][g4 * 4 + 3] * inv);
            *(uint2*)&ao[d] = pk;
        }
}

// ---------------------------------------------------------------------------
// output projection, bf16 MFMA + bias + residual (fp32 out).
// ---------------------------------------------------------------------------
__global__ __launch_bounds__(256) void proj_mfma_k(
    const unsigned short* __restrict__ wob, const unsigned short* __restrict__ att,
    const float* __restrict__ bias, const float* __restrict__ x,
    float* __restrict__ out)
{
    const int o0 = blockIdx.x * 128;
    const int p0 = blockIdx.y * 128;
    const int b  = blockIdx.z;
    const int t = threadIdx.x;
    const int wid = t >> 6, lane = t & 63, g = lane >> 4, li = lane & 15;
    const int wo = (wid >> 1) * 64, wp = (wid & 1) * 64;

    __shared__ char alds[16384];
    __shared__ char blds[16384];

    const int srow8 = t >> 3, sc16 = t & 7;
    const char* asrc = (const char*)wob + ((size_t)(o0 + srow8) * 256) * 2 + sc16 * 16;
    const char* bsrc = (const char*)att + (((size_t)b * HW + p0 + srow8) * 256) * 2 + sc16 * 16;

    float4 areg[4], breg[4];
    #pragma unroll
    for (int it = 0; it < 4; ++it) {
        areg[it] = *(const float4*)(asrc + (size_t)it * 32 * 512);
        breg[it] = *(const float4*)(bsrc + (size_t)it * 32 * 512);
    }

    float4v acc[4][4];
    #pragma unroll
    for (int mt = 0; mt < 4; ++mt)
        #pragma unroll
        for (int nt = 0; nt < 4; ++nt) acc[mt][nt] = (float4v){0.f, 0.f, 0.f, 0.f};

    for (int ks = 0; ks < 4; ++ks) {
        #pragma unroll
        for (int it = 0; it < 4; ++it) {
            const int row = it * 32 + srow8;
            const int dsw = row * 128 + ((sc16 * 16) ^ ((row & 7) << 4));
            *(float4*)(alds + dsw) = areg[it];
            *(float4*)(blds + dsw) = breg[it];
        }
        __syncthreads();
        if (ks < 3) {
            #pragma unroll
            for (int it = 0; it < 4; ++it) {
                areg[it] = *(const float4*)(asrc + (size_t)it * 32 * 512 + (ks + 1) * 128);
                breg[it] = *(const float4*)(bsrc + (size_t)it * 32 * 512 + (ks + 1) * 128);
            }
        }
        short8v af[4][2], bf[4][2];
        #pragma unroll
        for (int mt = 0; mt < 4; ++mt) {
            const int row = wo + mt * 16 + li;
            #pragma unroll
            for (int kc = 0; kc < 2; ++kc)
                af[mt][kc] = *(const short8v*)(alds + row * 128 + ((kc * 64 + g * 16) ^ ((row & 7) << 4)));
        }
        #pragma unroll
        for (int nt = 0; nt < 4; ++nt) {
            const int row = wp + nt * 16 + li;
            #pragma unroll
            for (int kc = 0; kc < 2; ++kc)
                bf[nt][kc] = *(const short8v*)(blds + row * 128 + ((kc * 64 + g * 16) ^ ((row & 7) << 4)));
        }
        #pragma unroll
        for (int mt = 0; mt < 4; ++mt)
            #pragma unroll
            for (int nt = 0; nt < 4; ++nt) {
                acc[mt][nt] = __builtin_amdgcn_mfma_f32_16x16x32_bf16(af[mt][0], bf[nt][0], acc[mt][nt], 0, 0, 0);
                acc[mt][nt] = __builtin_amdgcn_mfma_f32_16x16x32_bf16(af[mt][1], bf[nt][1], acc[mt][nt], 0, 0, 0);
            }
        __syncthreads();
    }

    #pragma unroll
    for (int mt = 0; mt < 4; ++mt) {
        const int o_b = o0 + wo + mt * 16 + g * 4;
        #pragma unroll
        for (int nt = 0; nt < 4; ++nt) {
            const int p = p0 + wp + nt * 16 + li;
            #pragma unroll
            for (int r = 0; r < 4; ++r) {
                const int o = o_b + r;
                const size_t ix = ((size_t)b * CIN + o) * HW + p;
                out[ix] = acc[mt][nt][r] + bias[o] + x[ix];
            }
        }
    }
}

extern "C" void kernel_launch(void* const* d_in, const int* in_sizes, int n_in,
                              void* d_out, int out_size, void* d_ws, size_t ws_size,
                              hipStream_t stream)
{
    const float* x     = (const float*)d_in[0];
    const float* w_qkv = (const float*)d_in[1];
    const float* w_out = (const float*)d_in[2];
    const float* b_out = (const float*)d_in[3];
    float* out = (float*)d_out;

    char* ws = (char*)d_ws;
    const size_t MB = 1024 * 1024;
    unsigned short* xt  = (unsigned short*)(ws);
    unsigned short* qb  = (unsigned short*)(ws + 8 * MB);
    unsigned short* kb  = (unsigned short*)(ws + 16 * MB);
    unsigned short* vb  = (unsigned short*)(ws + 24 * MB);
    unsigned short* att = (unsigned short*)(ws + 32 * MB);
    unsigned short* wqb = (unsigned short*)(ws + 40 * MB);
    unsigned short* wob = (unsigned short*)(ws + 40 * MB + 768 * 256 * 2);

    cast_w_k<<<256, 256, 0, stream>>>(w_qkv, w_out, wqb, wob);
    cast_x_k<<<dim3(64, 4, 4), 256, 0, stream>>>(x, xt);
    qkv_mfma_k<<<dim3(6, 32, 4), 256, 0, stream>>>(wqb, xt, qb, kb, vb);
    flash_mfma_k<<<dim3(32, 16), 256, 0, stream>>>(qb, kb, vb, att);
    proj_mfma_k<<<dim3(2, 32, 4), 256, 0, stream>>>(wob, att, b_out, x, out);
}